// Round 8
// baseline (1524.043 us; speedup 1.0000x reference)
//
#include <hip/hip_runtime.h>
#include <math.h>

#define NN 20000
#define NNP 20224   // padded to 158*128
#define NGRP2 158   // NNP/128
#define NE 320000
#define D 50
#define TOWERS 5
#define TD 250      // TOWERS*D
#define ASTR 256    // padded row stride for ai/aj
#define FOUT 10
#define EPS 1e-5f

// ------------------------------------------------------------------ setup
__global__ void k_deg(const int* __restrict__ dst, int* __restrict__ deg) {
    int e = blockIdx.x * 256 + threadIdx.x;
    if (e < NE) atomicAdd(&deg[dst[e]], 1);
}

__global__ void k_hist(const int* __restrict__ deg, int* __restrict__ hist) {
    int n = blockIdx.x * 256 + threadIdx.x;
    if (n < NN) atomicAdd(&hist[min(deg[n], 255)], 1);
}

__global__ void k_binscan(const int* __restrict__ hist, int* __restrict__ binbase) {
    __shared__ int b[256];
    int tid = threadIdx.x;
    b[tid] = hist[tid];
    __syncthreads();
    for (int off = 1; off < 256; off <<= 1) {
        int t = (tid >= off) ? b[tid - off] : 0;
        __syncthreads();
        b[tid] += t;
        __syncthreads();
    }
    binbase[tid] = b[tid] - hist[tid];   // exclusive
}

__global__ void k_scatter(const int* __restrict__ deg, const int* __restrict__ binbase,
                          int* __restrict__ cursorb, int* __restrict__ perm,
                          int* __restrict__ invp, int* __restrict__ deg_r) {
    int n = blockIdx.x * 256 + threadIdx.x;
    if (n < NN) {
        int d = min(deg[n], 255);
        int r = binbase[d] + atomicAdd(&cursorb[d], 1);
        perm[r] = n;
        invp[n] = r;
        deg_r[r] = deg[n];
    }
}

__global__ void k_scan(const int* __restrict__ deg, int* __restrict__ offs) {
    __shared__ int buf[1024];
    __shared__ int carry;
    int tid = threadIdx.x;
    if (tid == 0) carry = 0;
    __syncthreads();
    for (int base = 0; base < NN; base += 1024) {
        int i = base + tid;
        int v = (i < NN) ? deg[i] : 0;
        buf[tid] = v;
        __syncthreads();
        for (int off = 1; off < 1024; off <<= 1) {
            int t = (tid >= off) ? buf[tid - off] : 0;
            __syncthreads();
            buf[tid] += t;
            __syncthreads();
        }
        int excl = carry + buf[tid] - v;
        if (i < NN) offs[i] = excl;
        __syncthreads();
        if (tid == 0) carry += buf[1023];
        __syncthreads();
    }
    if (tid == 0) offs[NN] = carry;        // == NE
}

__global__ void k_csr(const int* __restrict__ src, const int* __restrict__ dst,
                      const int* __restrict__ offs, const int* __restrict__ invp,
                      int* __restrict__ cursor, int* __restrict__ csr_src) {
    int e = blockIdx.x * 256 + threadIdx.x;
    if (e < NE) {
        int rd = invp[dst[e]];
        int slot = atomicAdd(&cursor[rd], 1);
        csr_src[offs[rd] + slot] = invp[src[e]];
    }
}

__global__ void k_avglog(const int* __restrict__ deg, float* __restrict__ accum) {
    int n = blockIdx.x * 256 + threadIdx.x;
    float v = (n < NN) ? logf((float)deg[n] + 1.0f) : 0.0f;
    for (int o = 32; o > 0; o >>= 1) v += __shfl_down(v, o);
    __shared__ float wsum[4];
    int lane = threadIdx.x & 63, w = threadIdx.x >> 6;
    if (lane == 0) wsum[w] = v;
    __syncthreads();
    if (threadIdx.x == 0) atomicAdd(accum, wsum[0] + wsum[1] + wsum[2] + wsum[3]);
}

// embedding -> hT (feature-major, RANK space), zero pad columns
__global__ void k_emb(const int* __restrict__ x, const float* __restrict__ emb,
                      const int* __restrict__ perm, float* __restrict__ hT) {
    int idx = blockIdx.x * 256 + threadIdx.x;
    if (idx < D * NNP) {
        int c = idx / NNP, r = idx % NNP;
        hT[idx] = (r < NN) ? emb[x[perm[r]] * D + c] : 0.f;
    }
}

// transpose postW (all layers) into wT[l][t][200][32] (c = p*10+g, pad 30,31)
// and wxT[l][t][50][16] (c = g, pad 10..15) for scalar-broadcast GEMV.
__global__ void k_wt(const float* __restrict__ postW, float* __restrict__ wT,
                     float* __restrict__ wxT) {
    int idx = blockIdx.x * 256 + threadIdx.x;
    const int WTN = 4 * TOWERS * 200 * 32;
    if (idx < WTN) {
        int l = idx / (TOWERS * 200 * 32);
        int r = idx % (TOWERS * 200 * 32);
        int t = r / (200 * 32); r %= 200 * 32;
        int j = r / 32, c = r % 32;
        float v = 0.f;
        if (c < 30) {
            int p = c / 10, g = c % 10;
            v = postW[l * 32500 + (t * FOUT + g) * 650 + 50 + p * 200 + j];
        }
        wT[idx] = v;
    } else if (idx < WTN + 4 * TOWERS * 50 * 16) {
        int k = idx - WTN;
        int l = k / (TOWERS * 50 * 16);
        int r = k % (TOWERS * 50 * 16);
        int t = r / (50 * 16); r %= 50 * 16;
        int j = r / 16, c = r % 16;
        float v = 0.f;
        if (c < 10) v = postW[l * 32500 + (t * FOUT + c) * 650 + j];
        wxT[k] = v;
    }
}

// ------------------------------------------------------------- per layer
#define PRE_NT 64
__global__ __launch_bounds__(256) void k_pre(const float* __restrict__ hT,
                                             const float* __restrict__ preW, // [TD][2D]
                                             float* __restrict__ ai,
                                             float* __restrict__ aj) {
    __shared__ float xl[PRE_NT * 52];
    int n0 = blockIdx.x * PRE_NT;
    int nmax = min(PRE_NT, NN - n0);
    for (int k = threadIdx.x; k < PRE_NT * D; k += 256) {
        int f = k >> 6, nl = k & 63;
        xl[nl * 52 + f] = hT[(size_t)f * NNP + n0 + nl];
    }
    __syncthreads();
    int o = threadIdx.x;
    if (o < TD) {
        const float* w0 = preW + o * (2 * D);
        float wi[D], wj[D];
#pragma unroll
        for (int f = 0; f < D; ++f) { wi[f] = w0[f]; wj[f] = w0[D + f]; }
        for (int nl = 0; nl < nmax; ++nl) {
            const float* xv = &xl[nl * 52];
            float a0 = 0.f, a1 = 0.f;
#pragma unroll
            for (int f = 0; f < D; ++f) { a0 += xv[f] * wi[f]; a1 += xv[f] * wj[f]; }
            ai[(size_t)(n0 + nl) * ASTR + o] = a0;
            aj[(size_t)(n0 + nl) * ASTR + o] = a1;
        }
    } else if (o < ASTR) {
        for (int nl = 0; nl < nmax; ++nl) {
            ai[(size_t)(n0 + nl) * ASTR + o] = 0.f;
            aj[(size_t)(n0 + nl) * ASTR + o] = 0.f;
        }
    }
}

// Edge aggregation, RANK space (degree-sorted -> no tail divergence).
// Grid = 313 nodeblocks x 8 chunks (chunk in low bits, XCD-pinned).
// Block 512 = 8 waves; wave = 16 nodes x 4 float4-cols (lane = g*4+q):
// reads 64B-aligned per node-row, writes 4 x 64B coalesced segments.
__global__ __launch_bounds__(512) void k_agg(
    const float* __restrict__ aj, const int* __restrict__ offs,
    const int* __restrict__ csr_src, const float* __restrict__ ai,
    const float* __restrict__ preB, float* __restrict__ aggT) {
    int chunk = blockIdx.x & 7;
    int nb = blockIdx.x >> 3;
    int tid = threadIdx.x;
    int wave = tid >> 6, lane = tid & 63;
    int g = lane >> 2, q = lane & 3;
    int r = nb * 64 + (wave >> 1) * 16 + g;
    int coloff = chunk * 8 + (wave & 1) * 4 + q;
    bool ok = r < NN;
    int e0 = 0, dg = 0;
    if (ok) { e0 = offs[r]; dg = offs[r + 1] - e0; }
    int mdeg = dg;
#pragma unroll
    for (int o = 4; o < 64; o <<= 1) mdeg = min(mdeg, __shfl_xor(mdeg, o));

    const float4* ajv = (const float4*)aj;
    float s1x = 0.f, s1y = 0.f, s1z = 0.f, s1w = 0.f;
    float s2x = 0.f, s2y = 0.f, s2z = 0.f, s2w = 0.f;
    float mnx = INFINITY, mny = INFINITY, mnz = INFINITY, mnw = INFINITY;
    float mxx = -INFINITY, mxy = -INFINITY, mxz = -INFINITY, mxw = -INFINITY;

    int it = 0;
    for (; it < mdeg; ++it) {                 // uniform part (sorted degrees)
        int s = csr_src[e0 + it];
        float4 v = ajv[((unsigned)s << 6) + coloff];
        s1x += v.x; s1y += v.y; s1z += v.z; s1w += v.w;
        s2x = fmaf(v.x, v.x, s2x); s2y = fmaf(v.y, v.y, s2y);
        s2z = fmaf(v.z, v.z, s2z); s2w = fmaf(v.w, v.w, s2w);
        mnx = fminf(mnx, v.x); mny = fminf(mny, v.y);
        mnz = fminf(mnz, v.z); mnw = fminf(mnw, v.w);
        mxx = fmaxf(mxx, v.x); mxy = fmaxf(mxy, v.y);
        mxz = fmaxf(mxz, v.z); mxw = fmaxf(mxw, v.w);
    }
    while (__any(it < dg)) {                  // tiny tail (bin boundaries)
        bool valid = it < dg;
        int s = csr_src[valid ? e0 + it : e0];
        float4 v = ajv[((unsigned)s << 6) + coloff];
        float zx = valid ? v.x : 0.f, zy = valid ? v.y : 0.f;
        float zz = valid ? v.z : 0.f, zw = valid ? v.w : 0.f;
        s1x += zx; s1y += zy; s1z += zz; s1w += zw;
        s2x = fmaf(zx, zx, s2x); s2y = fmaf(zy, zy, s2y);
        s2z = fmaf(zz, zz, s2z); s2w = fmaf(zw, zw, s2w);
        mnx = fminf(mnx, valid ? v.x : INFINITY);
        mny = fminf(mny, valid ? v.y : INFINITY);
        mnz = fminf(mnz, valid ? v.z : INFINITY);
        mnw = fminf(mnw, valid ? v.w : INFINITY);
        mxx = fmaxf(mxx, valid ? v.x : -INFINITY);
        mxy = fmaxf(mxy, valid ? v.y : -INFINITY);
        mxz = fmaxf(mxz, valid ? v.z : -INFINITY);
        mxw = fmaxf(mxw, valid ? v.w : -INFINITY);
        ++it;
    }

    if (ok) {
        float inv = 1.0f / (float)max(dg, 1);
        float m1a[4], mna[4], mxa[4], sda[4];
        m1a[0] = s1x * inv; m1a[1] = s1y * inv; m1a[2] = s1z * inv; m1a[3] = s1w * inv;
        sda[0] = sqrtf(fmaxf(s2x * inv - m1a[0] * m1a[0], 0.f) + EPS);
        sda[1] = sqrtf(fmaxf(s2y * inv - m1a[1] * m1a[1], 0.f) + EPS);
        sda[2] = sqrtf(fmaxf(s2z * inv - m1a[2] * m1a[2], 0.f) + EPS);
        sda[3] = sqrtf(fmaxf(s2w * inv - m1a[3] * m1a[3], 0.f) + EPS);
        mna[0] = mnx; mna[1] = mny; mna[2] = mnz; mna[3] = mnw;
        mxa[0] = mxx; mxa[1] = mxy; mxa[2] = mxz; mxa[3] = mxw;
        float4 aiv = ((const float4*)ai)[(size_t)r * 64 + coloff];
        float aia[4] = {aiv.x, aiv.y, aiv.z, aiv.w};
        int f0 = coloff * 4;
#pragma unroll
        for (int k = 0; k < 4; ++k) {
            int f = f0 + k;
            if (f < TD) {
                float base;
                if (dg > 0) {
                    base = aia[k] + preB[f];
                } else {
                    base = 0.f;
                    m1a[k] = 0.f; mna[k] = 0.f; mxa[k] = 0.f;
                }
                int t = f / 50, gg = f - t * 50;
                float* col = aggT + (size_t)(t * 200 + gg) * NNP + r;
                col[0]                 = m1a[k] + base;
                col[(size_t)50 * NNP]  = mna[k] + base;
                col[(size_t)100 * NNP] = mxa[k] + base;
                col[(size_t)150 * NNP] = sda[k];
            }
        }
    }
}

// post-NN: thread-per-node GEMV; weights via wave-uniform (scalar) loads
// from pre-transposed wT/wxT. Grid = NGRP2 x TOWERS, block 128, no LDS.
__global__ __launch_bounds__(128) void k_post(
    const float* __restrict__ hT, const float* __restrict__ aggT,
    const int* __restrict__ offs,
    const float* __restrict__ wT,    // [T][200][32]
    const float* __restrict__ wxT,   // [T][50][16]
    const float* __restrict__ postB, // [50]
    float* __restrict__ bnbuf,       // [0:100) zeroed here; [100]=avg_log
    float* __restrict__ yT) {
    int t = blockIdx.x / NGRP2;
    int grp = blockIdx.x - t * NGRP2;
    int tid = threadIdx.x;
    int n = grp * 128 + tid;
    if (blockIdx.x == 0 && tid < 100) bnbuf[tid] = 0.f;   // for k_lin's atomics

    float acc[32];
#pragma unroll
    for (int i = 0; i < 32; ++i) acc[i] = 0.f;
    const float* aggcol = aggT + (size_t)(t * 200) * NNP + n;
    const float4* wv = (const float4*)(wT + t * 200 * 32);
#pragma unroll 2
    for (int j = 0; j < 200; ++j) {
        float a = aggcol[(size_t)j * NNP];
        float4 w0 = wv[j * 8 + 0], w1 = wv[j * 8 + 1], w2 = wv[j * 8 + 2],
               w3 = wv[j * 8 + 3], w4 = wv[j * 8 + 4], w5 = wv[j * 8 + 5],
               w6 = wv[j * 8 + 6], w7 = wv[j * 8 + 7];
        acc[0] = fmaf(a, w0.x, acc[0]);   acc[1] = fmaf(a, w0.y, acc[1]);
        acc[2] = fmaf(a, w0.z, acc[2]);   acc[3] = fmaf(a, w0.w, acc[3]);
        acc[4] = fmaf(a, w1.x, acc[4]);   acc[5] = fmaf(a, w1.y, acc[5]);
        acc[6] = fmaf(a, w1.z, acc[6]);   acc[7] = fmaf(a, w1.w, acc[7]);
        acc[8] = fmaf(a, w2.x, acc[8]);   acc[9] = fmaf(a, w2.y, acc[9]);
        acc[10] = fmaf(a, w2.z, acc[10]); acc[11] = fmaf(a, w2.w, acc[11]);
        acc[12] = fmaf(a, w3.x, acc[12]); acc[13] = fmaf(a, w3.y, acc[13]);
        acc[14] = fmaf(a, w3.z, acc[14]); acc[15] = fmaf(a, w3.w, acc[15]);
        acc[16] = fmaf(a, w4.x, acc[16]); acc[17] = fmaf(a, w4.y, acc[17]);
        acc[18] = fmaf(a, w4.z, acc[18]); acc[19] = fmaf(a, w4.w, acc[19]);
        acc[20] = fmaf(a, w5.x, acc[20]); acc[21] = fmaf(a, w5.y, acc[21]);
        acc[22] = fmaf(a, w5.z, acc[22]); acc[23] = fmaf(a, w5.w, acc[23]);
        acc[24] = fmaf(a, w6.x, acc[24]); acc[25] = fmaf(a, w6.y, acc[25]);
        acc[26] = fmaf(a, w6.z, acc[26]); acc[27] = fmaf(a, w6.w, acc[27]);
        acc[28] = fmaf(a, w7.x, acc[28]); acc[29] = fmaf(a, w7.y, acc[29]);
    }
    float xacc[10];
#pragma unroll
    for (int i = 0; i < 10; ++i) xacc[i] = 0.f;
    const float4* wxv = (const float4*)(wxT + t * 50 * 16);
#pragma unroll 2
    for (int j = 0; j < 50; ++j) {
        float a = hT[(size_t)j * NNP + n];
        float4 x0 = wxv[j * 4 + 0], x1 = wxv[j * 4 + 1], x2 = wxv[j * 4 + 2];
        xacc[0] = fmaf(a, x0.x, xacc[0]); xacc[1] = fmaf(a, x0.y, xacc[1]);
        xacc[2] = fmaf(a, x0.z, xacc[2]); xacc[3] = fmaf(a, x0.w, xacc[3]);
        xacc[4] = fmaf(a, x1.x, xacc[4]); xacc[5] = fmaf(a, x1.y, xacc[5]);
        xacc[6] = fmaf(a, x1.z, xacc[6]); xacc[7] = fmaf(a, x1.w, xacc[7]);
        xacc[8] = fmaf(a, x2.x, xacc[8]); xacc[9] = fmaf(a, x2.y, xacc[9]);
    }
    if (n < NN) {
        int dgn = offs[n + 1] - offs[n];
        float cnt = (float)max(dgn, 1);
        float sc = logf(cnt + 1.0f) / (bnbuf[100] * (1.0f / NN));
        float isc = 1.0f / sc;
#pragma unroll
        for (int g = 0; g < 10; ++g)
            yT[(size_t)(t * FOUT + g) * NNP + n] =
                postB[t * FOUT + g] + xacc[g] + acc[g] + sc * acc[10 + g] + isc * acc[20 + g];
    }
}

// 50x50 linear + fused BN stats (wave-reduce + global atomics).
__global__ __launch_bounds__(128) void k_lin(
    const float* __restrict__ yT, const float* __restrict__ linW,
    const float* __restrict__ linB, float* __restrict__ hrawT,
    float* __restrict__ bn) {
    int tid = threadIdx.x;
    int n = blockIdx.x * 128 + tid;
    int lane = tid & 63;
    float y[50];
#pragma unroll
    for (int q = 0; q < 50; ++q) y[q] = yT[(size_t)q * NNP + n];
    bool ok = n < NN;
    for (int c = 0; c < 50; ++c) {
        float a = linB[c];
        const float* w = linW + c * 50;
#pragma unroll
        for (int q = 0; q < 50; ++q) a = fmaf(w[q], y[q], a);
        if (ok) hrawT[(size_t)c * NNP + n] = a;
        float am = ok ? a : 0.f;
        float aq = am * am;
        for (int o = 32; o > 0; o >>= 1) {
            am += __shfl_down(am, o);
            aq += __shfl_down(aq, o);
        }
        if (lane == 0) {
            atomicAdd(&bn[c], am);
            atomicAdd(&bn[50 + c], aq);
        }
    }
}

__global__ void k_bnapply(const float* __restrict__ hrawT, const float* __restrict__ bn,
                          const float* __restrict__ gamma, const float* __restrict__ beta,
                          float* __restrict__ hT) {
    int idx = blockIdx.x * 256 + threadIdx.x;
    if (idx < D * NNP) {
        int c = idx / NNP, n = idx % NNP;
        float mean = bn[c] * (1.0f / NN);
        float var = bn[50 + c] * (1.0f / NN) - mean * mean;
        float v = gamma[c] * (hrawT[idx] - mean) * rsqrtf(var + EPS) + beta[c];
        hT[idx] = (n < NN) ? fmaxf(v, 0.f) : 0.f;
    }
}

__global__ void k_mlp(const float* __restrict__ hT, const int* __restrict__ perm,
                      const float* __restrict__ W1, const float* __restrict__ b1,
                      const float* __restrict__ W2, const float* __restrict__ b2,
                      float* __restrict__ out) {
    int n = blockIdx.x * 256 + threadIdx.x;
    if (n >= NN) return;
    float hv[50];
#pragma unroll
    for (int f = 0; f < 50; ++f) hv[f] = hT[(size_t)f * NNP + n];
    float s = b2[0];
    for (int o = 0; o < 25; ++o) {
        float a = b1[o];
        const float* w = W1 + o * 50;
#pragma unroll
        for (int f = 0; f < 50; ++f) a += w[f] * hv[f];
        s += W2[o] * fmaxf(a, 0.f);
    }
    out[perm[n]] = 1.0f / (1.0f + expf(-s));
}

// ------------------------------------------------------------------ launch
extern "C" void kernel_launch(void* const* d_in, const int* in_sizes, int n_in,
                              void* d_out, int out_size, void* d_ws, size_t ws_size,
                              hipStream_t stream) {
    const int* x = (const int*)d_in[0];
    const int* ei = (const int*)d_in[1];
    const int* src = ei;
    const int* dst = ei + NE;
    const float* emb   = (const float*)d_in[4];
    const float* preW  = (const float*)d_in[5];
    const float* preB  = (const float*)d_in[6];
    const float* postW = (const float*)d_in[7];
    const float* postB = (const float*)d_in[8];
    const float* linW  = (const float*)d_in[9];
    const float* linB  = (const float*)d_in[10];
    const float* gamma = (const float*)d_in[11];
    const float* beta  = (const float*)d_in[12];
    const float* W1 = (const float*)d_in[13];
    const float* b1 = (const float*)d_in[14];
    const float* W2 = (const float*)d_in[15];
    const float* b2 = (const float*)d_in[16];
    float* outp = (float*)d_out;

    char* wsp = (char*)d_ws;
    size_t off = 0;
    auto alloc = [&](size_t bytes) {
        void* p = wsp + off;
        off = (off + bytes + 1023) & ~(size_t)1023;
        return p;
    };
    int* deg     = (int*)alloc(NN * 4);
    int* cursor  = (int*)alloc(NN * 4);
    int* offs    = (int*)alloc((NN + 1) * 4);
    int* csr     = (int*)alloc(NE * 4);
    int* perm    = (int*)alloc(NN * 4);
    int* invp    = (int*)alloc(NN * 4);
    int* deg_r   = (int*)alloc(NN * 4);
    int* hist    = (int*)alloc(256 * 4);
    int* binbase = (int*)alloc(256 * 4);
    int* cursorb = (int*)alloc(256 * 4);
    float* bn    = (float*)alloc(512);
    float* hT    = (float*)alloc((size_t)D * NNP * 4);
    float* hrawT = (float*)alloc((size_t)D * NNP * 4);
    float* yT    = (float*)alloc((size_t)D * NNP * 4);
    float* ai    = (float*)alloc((size_t)NN * ASTR * 4);
    float* aj    = (float*)alloc((size_t)NN * ASTR * 4);
    float* wT    = (float*)alloc((size_t)4 * TOWERS * 200 * 32 * 4);
    float* wxT   = (float*)alloc((size_t)4 * TOWERS * 50 * 16 * 4);
    float* aggT  = (float*)alloc((size_t)1000 * NNP * 4);
    (void)ws_size; (void)in_sizes; (void)n_in; (void)out_size;

    hipMemsetAsync(deg, 0, NN * 4, stream);
    hipMemsetAsync(cursor, 0, NN * 4, stream);
    hipMemsetAsync(hist, 0, 256 * 4, stream);
    hipMemsetAsync(cursorb, 0, 256 * 4, stream);
    hipMemsetAsync(bn, 0, 512, stream);

    k_deg<<<(NE + 255) / 256, 256, 0, stream>>>(dst, deg);
    k_hist<<<(NN + 255) / 256, 256, 0, stream>>>(deg, hist);
    k_binscan<<<1, 256, 0, stream>>>(hist, binbase);
    k_scatter<<<(NN + 255) / 256, 256, 0, stream>>>(deg, binbase, cursorb, perm, invp, deg_r);
    k_scan<<<1, 1024, 0, stream>>>(deg_r, offs);
    k_csr<<<(NE + 255) / 256, 256, 0, stream>>>(src, dst, offs, invp, cursor, csr);
    k_avglog<<<(NN + 255) / 256, 256, 0, stream>>>(deg, bn + 100);
    k_emb<<<(D * NNP + 255) / 256, 256, 0, stream>>>(x, emb, perm, hT);
    k_wt<<<(4 * TOWERS * 200 * 32 + 4 * TOWERS * 50 * 16 + 255) / 256, 256, 0, stream>>>(postW, wT, wxT);

    int aggblocks = 313 * 8;
    for (int l = 0; l < 4; ++l) {
        k_pre<<<313, 256, 0, stream>>>(hT, preW + l * TD * 100, ai, aj);
        k_agg<<<aggblocks, 512, 0, stream>>>(aj, offs, csr, ai, preB + l * TD, aggT);
        k_post<<<NGRP2 * TOWERS, 128, 0, stream>>>(hT, aggT, offs,
                                                   wT + l * TOWERS * 200 * 32,
                                                   wxT + l * TOWERS * 50 * 16,
                                                   postB + l * 50, bn, yT);
        k_lin<<<NGRP2, 128, 0, stream>>>(yT, linW + l * 2500, linB + l * 50, hrawT, bn);
        k_bnapply<<<(D * NNP + 255) / 256, 256, 0, stream>>>(hrawT, bn, gamma + l * 50,
                                                             beta + l * 50, hT);
    }
    k_mlp<<<(NN + 255) / 256, 256, 0, stream>>>(hT, perm, W1, b1, W2, b2, outp);
}

// Round 9
// 1117.940 us; speedup vs baseline: 1.3633x; 1.3633x over previous
//
#include <hip/hip_runtime.h>
#include <math.h>

#define NN 20000
#define NNP 20224   // padded to 158*128 (= 79*256)
#define NGRP2 158   // NNP/128
#define NE 320000
#define D 50
#define TOWERS 5
#define TD 250      // TOWERS*D
#define ASTR 256    // padded row stride for ai/aj
#define FOUT 10
#define EPS 1e-5f

// ------------------------------------------------------------------ setup
__global__ void k_deg(const int* __restrict__ dst, int* __restrict__ deg) {
    int e = blockIdx.x * 256 + threadIdx.x;
    if (e < NE) atomicAdd(&deg[dst[e]], 1);
}

__global__ void k_hist(const int* __restrict__ deg, int* __restrict__ hist) {
    int n = blockIdx.x * 256 + threadIdx.x;
    if (n < NN) atomicAdd(&hist[min(deg[n], 255)], 1);
}

__global__ void k_binscan(const int* __restrict__ hist, int* __restrict__ binbase) {
    __shared__ int b[256];
    int tid = threadIdx.x;
    b[tid] = hist[tid];
    __syncthreads();
    for (int off = 1; off < 256; off <<= 1) {
        int t = (tid >= off) ? b[tid - off] : 0;
        __syncthreads();
        b[tid] += t;
        __syncthreads();
    }
    binbase[tid] = b[tid] - hist[tid];   // exclusive
}

__global__ void k_scatter(const int* __restrict__ deg, const int* __restrict__ binbase,
                          int* __restrict__ cursorb, int* __restrict__ perm,
                          int* __restrict__ invp, int* __restrict__ deg_r) {
    int n = blockIdx.x * 256 + threadIdx.x;
    if (n < NN) {
        int d = min(deg[n], 255);
        int r = binbase[d] + atomicAdd(&cursorb[d], 1);
        perm[r] = n;
        invp[n] = r;
        deg_r[r] = deg[n];
    }
}

__global__ void k_scan(const int* __restrict__ deg, int* __restrict__ offs) {
    __shared__ int buf[1024];
    __shared__ int carry;
    int tid = threadIdx.x;
    if (tid == 0) carry = 0;
    __syncthreads();
    for (int base = 0; base < NN; base += 1024) {
        int i = base + tid;
        int v = (i < NN) ? deg[i] : 0;
        buf[tid] = v;
        __syncthreads();
        for (int off = 1; off < 1024; off <<= 1) {
            int t = (tid >= off) ? buf[tid - off] : 0;
            __syncthreads();
            buf[tid] += t;
            __syncthreads();
        }
        int excl = carry + buf[tid] - v;
        if (i < NN) offs[i] = excl;
        __syncthreads();
        if (tid == 0) carry += buf[1023];
        __syncthreads();
    }
    if (tid == 0) offs[NN] = carry;        // == NE
}

__global__ void k_csr(const int* __restrict__ src, const int* __restrict__ dst,
                      const int* __restrict__ offs, const int* __restrict__ invp,
                      int* __restrict__ cursor, int* __restrict__ csr_src) {
    int e = blockIdx.x * 256 + threadIdx.x;
    if (e < NE) {
        int rd = invp[dst[e]];
        int slot = atomicAdd(&cursor[rd], 1);
        csr_src[offs[rd] + slot] = invp[src[e]];
    }
}

__global__ void k_avglog(const int* __restrict__ deg, float* __restrict__ accum) {
    int n = blockIdx.x * 256 + threadIdx.x;
    float v = (n < NN) ? logf((float)deg[n] + 1.0f) : 0.0f;
    for (int o = 32; o > 0; o >>= 1) v += __shfl_down(v, o);
    __shared__ float wsum[4];
    int lane = threadIdx.x & 63, w = threadIdx.x >> 6;
    if (lane == 0) wsum[w] = v;
    __syncthreads();
    if (threadIdx.x == 0) atomicAdd(accum, wsum[0] + wsum[1] + wsum[2] + wsum[3]);
}

// embedding -> hT (feature-major, RANK space), zero pad columns
__global__ void k_emb(const int* __restrict__ x, const float* __restrict__ emb,
                      const int* __restrict__ perm, float* __restrict__ hT) {
    int idx = blockIdx.x * 256 + threadIdx.x;
    if (idx < D * NNP) {
        int c = idx / NNP, r = idx % NNP;
        hT[idx] = (r < NN) ? emb[x[perm[r]] * D + c] : 0.f;
    }
}

// transpose postW (all layers) into wT[l][t][200][32] (c = p*10+g, pad 30,31)
// and wxT[l][t][50][16] (c = g, pad 10..15) for scalar-broadcast GEMV.
__global__ void k_wt(const float* __restrict__ postW, float* __restrict__ wT,
                     float* __restrict__ wxT) {
    int idx = blockIdx.x * 256 + threadIdx.x;
    const int WTN = 4 * TOWERS * 200 * 32;
    if (idx < WTN) {
        int l = idx / (TOWERS * 200 * 32);
        int r = idx % (TOWERS * 200 * 32);
        int t = r / (200 * 32); r %= 200 * 32;
        int j = r / 32, c = r % 32;
        float v = 0.f;
        if (c < 30) {
            int p = c / 10, g = c % 10;
            v = postW[l * 32500 + (t * FOUT + g) * 650 + 50 + p * 200 + j];
        }
        wT[idx] = v;
    } else if (idx < WTN + 4 * TOWERS * 50 * 16) {
        int k = idx - WTN;
        int l = k / (TOWERS * 50 * 16);
        int r = k % (TOWERS * 50 * 16);
        int t = r / (50 * 16); r %= 50 * 16;
        int j = r / 16, c = r % 16;
        float v = 0.f;
        if (c < 10) v = postW[l * 32500 + (t * FOUT + c) * 650 + j];
        wxT[k] = v;
    }
}

// ------------------------------------------------------------- per layer
#define PRE_NT 64
__global__ __launch_bounds__(256) void k_pre(const float* __restrict__ hT,
                                             const float* __restrict__ preW, // [TD][2D]
                                             float* __restrict__ ai,
                                             float* __restrict__ aj) {
    __shared__ float xl[PRE_NT * 52];
    int n0 = blockIdx.x * PRE_NT;
    int nmax = min(PRE_NT, NN - n0);
    for (int k = threadIdx.x; k < PRE_NT * D; k += 256) {
        int f = k >> 6, nl = k & 63;
        xl[nl * 52 + f] = hT[(size_t)f * NNP + n0 + nl];
    }
    __syncthreads();
    int o = threadIdx.x;
    if (o < TD) {
        const float* w0 = preW + o * (2 * D);
        float wi[D], wj[D];
#pragma unroll
        for (int f = 0; f < D; ++f) { wi[f] = w0[f]; wj[f] = w0[D + f]; }
        for (int nl = 0; nl < nmax; ++nl) {
            const float* xv = &xl[nl * 52];
            float a0 = 0.f, a1 = 0.f;
#pragma unroll
            for (int f = 0; f < D; ++f) { a0 += xv[f] * wi[f]; a1 += xv[f] * wj[f]; }
            ai[(size_t)(n0 + nl) * ASTR + o] = a0;
            aj[(size_t)(n0 + nl) * ASTR + o] = a1;
        }
    } else if (o < ASTR) {
        for (int nl = 0; nl < nmax; ++nl) {
            ai[(size_t)(n0 + nl) * ASTR + o] = 0.f;
            aj[(size_t)(n0 + nl) * ASTR + o] = 0.f;
        }
    }
}

// Edge aggregation, RANK space (degree-sorted -> no tail divergence).
// Grid = 313 nodeblocks x 8 chunks (chunk in low bits, XCD-pinned).
// Block 512 = 8 waves; wave = 16 nodes x 4 float4-cols (lane = g*4+q).
__global__ __launch_bounds__(512) void k_agg(
    const float* __restrict__ aj, const int* __restrict__ offs,
    const int* __restrict__ csr_src, const float* __restrict__ ai,
    const float* __restrict__ preB, float* __restrict__ aggT) {
    int chunk = blockIdx.x & 7;
    int nb = blockIdx.x >> 3;
    int tid = threadIdx.x;
    int wave = tid >> 6, lane = tid & 63;
    int g = lane >> 2, q = lane & 3;
    int r = nb * 64 + (wave >> 1) * 16 + g;
    int coloff = chunk * 8 + (wave & 1) * 4 + q;
    bool ok = r < NN;
    int e0 = 0, dg = 0;
    if (ok) { e0 = offs[r]; dg = offs[r + 1] - e0; }
    int mdeg = dg;
#pragma unroll
    for (int o = 4; o < 64; o <<= 1) mdeg = min(mdeg, __shfl_xor(mdeg, o));

    const float4* ajv = (const float4*)aj;
    float s1x = 0.f, s1y = 0.f, s1z = 0.f, s1w = 0.f;
    float s2x = 0.f, s2y = 0.f, s2z = 0.f, s2w = 0.f;
    float mnx = INFINITY, mny = INFINITY, mnz = INFINITY, mnw = INFINITY;
    float mxx = -INFINITY, mxy = -INFINITY, mxz = -INFINITY, mxw = -INFINITY;

    int it = 0;
    for (; it < mdeg; ++it) {                 // uniform part (sorted degrees)
        int s = csr_src[e0 + it];
        float4 v = ajv[((unsigned)s << 6) + coloff];
        s1x += v.x; s1y += v.y; s1z += v.z; s1w += v.w;
        s2x = fmaf(v.x, v.x, s2x); s2y = fmaf(v.y, v.y, s2y);
        s2z = fmaf(v.z, v.z, s2z); s2w = fmaf(v.w, v.w, s2w);
        mnx = fminf(mnx, v.x); mny = fminf(mny, v.y);
        mnz = fminf(mnz, v.z); mnw = fminf(mnw, v.w);
        mxx = fmaxf(mxx, v.x); mxy = fmaxf(mxy, v.y);
        mxz = fmaxf(mxz, v.z); mxw = fmaxf(mxw, v.w);
    }
    while (__any(it < dg)) {                  // tiny tail (bin boundaries)
        bool valid = it < dg;
        int s = csr_src[valid ? e0 + it : e0];
        float4 v = ajv[((unsigned)s << 6) + coloff];
        float zx = valid ? v.x : 0.f, zy = valid ? v.y : 0.f;
        float zz = valid ? v.z : 0.f, zw = valid ? v.w : 0.f;
        s1x += zx; s1y += zy; s1z += zz; s1w += zw;
        s2x = fmaf(zx, zx, s2x); s2y = fmaf(zy, zy, s2y);
        s2z = fmaf(zz, zz, s2z); s2w = fmaf(zw, zw, s2w);
        mnx = fminf(mnx, valid ? v.x : INFINITY);
        mny = fminf(mny, valid ? v.y : INFINITY);
        mnz = fminf(mnz, valid ? v.z : INFINITY);
        mnw = fminf(mnw, valid ? v.w : INFINITY);
        mxx = fmaxf(mxx, valid ? v.x : -INFINITY);
        mxy = fmaxf(mxy, valid ? v.y : -INFINITY);
        mxz = fmaxf(mxz, valid ? v.z : -INFINITY);
        mxw = fmaxf(mxw, valid ? v.w : -INFINITY);
        ++it;
    }

    if (ok) {
        float inv = 1.0f / (float)max(dg, 1);
        float m1a[4], mna[4], mxa[4], sda[4];
        m1a[0] = s1x * inv; m1a[1] = s1y * inv; m1a[2] = s1z * inv; m1a[3] = s1w * inv;
        sda[0] = sqrtf(fmaxf(s2x * inv - m1a[0] * m1a[0], 0.f) + EPS);
        sda[1] = sqrtf(fmaxf(s2y * inv - m1a[1] * m1a[1], 0.f) + EPS);
        sda[2] = sqrtf(fmaxf(s2z * inv - m1a[2] * m1a[2], 0.f) + EPS);
        sda[3] = sqrtf(fmaxf(s2w * inv - m1a[3] * m1a[3], 0.f) + EPS);
        mna[0] = mnx; mna[1] = mny; mna[2] = mnz; mna[3] = mnw;
        mxa[0] = mxx; mxa[1] = mxy; mxa[2] = mxz; mxa[3] = mxw;
        float4 aiv = ((const float4*)ai)[(size_t)r * 64 + coloff];
        float aia[4] = {aiv.x, aiv.y, aiv.z, aiv.w};
        int f0 = coloff * 4;
#pragma unroll
        for (int k = 0; k < 4; ++k) {
            int f = f0 + k;
            if (f < TD) {
                float base;
                if (dg > 0) {
                    base = aia[k] + preB[f];
                } else {
                    base = 0.f;
                    m1a[k] = 0.f; mna[k] = 0.f; mxa[k] = 0.f;
                }
                int t = f / 50, gg = f - t * 50;
                float* col = aggT + (size_t)(t * 200 + gg) * NNP + r;
                col[0]                 = m1a[k] + base;
                col[(size_t)50 * NNP]  = mna[k] + base;
                col[(size_t)100 * NNP] = mxa[k] + base;
                col[(size_t)150 * NNP] = sda[k];
            }
        }
    }
}

// post-NN: thread-per-node GEMV; weights via wave-uniform loads from
// pre-transposed wT/wxT. Grid = NGRP2 x TOWERS, block 128, no LDS.
__global__ __launch_bounds__(128) void k_post(
    const float* __restrict__ hT, const float* __restrict__ aggT,
    const int* __restrict__ offs,
    const float* __restrict__ wT,    // [T][200][32]
    const float* __restrict__ wxT,   // [T][50][16]
    const float* __restrict__ postB, // [50]
    const float* __restrict__ avg_accum, float* __restrict__ yT) {
    int t = blockIdx.x / NGRP2;
    int grp = blockIdx.x - t * NGRP2;
    int tid = threadIdx.x;
    int n = grp * 128 + tid;

    float acc[32];
#pragma unroll
    for (int i = 0; i < 32; ++i) acc[i] = 0.f;
    const float* aggcol = aggT + (size_t)(t * 200) * NNP + n;
    const float4* wv = (const float4*)(wT + t * 200 * 32);
#pragma unroll 2
    for (int j = 0; j < 200; ++j) {
        float a = aggcol[(size_t)j * NNP];
        float4 w0 = wv[j * 8 + 0], w1 = wv[j * 8 + 1], w2 = wv[j * 8 + 2],
               w3 = wv[j * 8 + 3], w4 = wv[j * 8 + 4], w5 = wv[j * 8 + 5],
               w6 = wv[j * 8 + 6], w7 = wv[j * 8 + 7];
        acc[0] = fmaf(a, w0.x, acc[0]);   acc[1] = fmaf(a, w0.y, acc[1]);
        acc[2] = fmaf(a, w0.z, acc[2]);   acc[3] = fmaf(a, w0.w, acc[3]);
        acc[4] = fmaf(a, w1.x, acc[4]);   acc[5] = fmaf(a, w1.y, acc[5]);
        acc[6] = fmaf(a, w1.z, acc[6]);   acc[7] = fmaf(a, w1.w, acc[7]);
        acc[8] = fmaf(a, w2.x, acc[8]);   acc[9] = fmaf(a, w2.y, acc[9]);
        acc[10] = fmaf(a, w2.z, acc[10]); acc[11] = fmaf(a, w2.w, acc[11]);
        acc[12] = fmaf(a, w3.x, acc[12]); acc[13] = fmaf(a, w3.y, acc[13]);
        acc[14] = fmaf(a, w3.z, acc[14]); acc[15] = fmaf(a, w3.w, acc[15]);
        acc[16] = fmaf(a, w4.x, acc[16]); acc[17] = fmaf(a, w4.y, acc[17]);
        acc[18] = fmaf(a, w4.z, acc[18]); acc[19] = fmaf(a, w4.w, acc[19]);
        acc[20] = fmaf(a, w5.x, acc[20]); acc[21] = fmaf(a, w5.y, acc[21]);
        acc[22] = fmaf(a, w5.z, acc[22]); acc[23] = fmaf(a, w5.w, acc[23]);
        acc[24] = fmaf(a, w6.x, acc[24]); acc[25] = fmaf(a, w6.y, acc[25]);
        acc[26] = fmaf(a, w6.z, acc[26]); acc[27] = fmaf(a, w6.w, acc[27]);
        acc[28] = fmaf(a, w7.x, acc[28]); acc[29] = fmaf(a, w7.y, acc[29]);
    }
    float xacc[10];
#pragma unroll
    for (int i = 0; i < 10; ++i) xacc[i] = 0.f;
    const float4* wxv = (const float4*)(wxT + t * 50 * 16);
#pragma unroll 2
    for (int j = 0; j < 50; ++j) {
        float a = hT[(size_t)j * NNP + n];
        float4 x0 = wxv[j * 4 + 0], x1 = wxv[j * 4 + 1], x2 = wxv[j * 4 + 2];
        xacc[0] = fmaf(a, x0.x, xacc[0]); xacc[1] = fmaf(a, x0.y, xacc[1]);
        xacc[2] = fmaf(a, x0.z, xacc[2]); xacc[3] = fmaf(a, x0.w, xacc[3]);
        xacc[4] = fmaf(a, x1.x, xacc[4]); xacc[5] = fmaf(a, x1.y, xacc[5]);
        xacc[6] = fmaf(a, x1.z, xacc[6]); xacc[7] = fmaf(a, x1.w, xacc[7]);
        xacc[8] = fmaf(a, x2.x, xacc[8]); xacc[9] = fmaf(a, x2.y, xacc[9]);
    }
    if (n < NN) {
        int dgn = offs[n + 1] - offs[n];
        float cnt = (float)max(dgn, 1);
        float sc = logf(cnt + 1.0f) / (avg_accum[0] * (1.0f / NN));
        float isc = 1.0f / sc;
#pragma unroll
        for (int g = 0; g < 10; ++g)
            yT[(size_t)(t * FOUT + g) * NNP + n] =
                postB[t * FOUT + g] + xacc[g] + acc[g] + sc * acc[10 + g] + isc * acc[20 + g];
    }
}

// 50x50 linear (pure), LDS-staged weights. 79 blocks x 256 threads.
__global__ __launch_bounds__(256) void k_lin(
    const float* __restrict__ yT, const float* __restrict__ linW,
    const float* __restrict__ linB, float* __restrict__ hrawT) {
    __shared__ float wl[2500];
    __shared__ float bl[50];
    int tid = threadIdx.x;
    int n = blockIdx.x * 256 + tid;
    for (int i = tid; i < 2500; i += 256) wl[i] = linW[i];
    if (tid < 50) bl[tid] = linB[tid];
    __syncthreads();
    float y[50];
#pragma unroll
    for (int q = 0; q < 50; ++q) y[q] = yT[(size_t)q * NNP + n];
    for (int c = 0; c < 50; ++c) {
        float a = bl[c];
        const float* w = wl + c * 50;
#pragma unroll
        for (int q = 0; q < 50; ++q) a = fmaf(w[q], y[q], a);
        hrawT[(size_t)c * NNP + n] = a;
    }
}

// BN stats: one block per channel, coalesced row reduce, direct write.
__global__ __launch_bounds__(256) void k_bnstats(const float* __restrict__ hrawT,
                                                 float* __restrict__ bn) {
    int c = blockIdx.x;
    int tid = threadIdx.x;
    const float* row = hrawT + (size_t)c * NNP;
    float s = 0.f, sq = 0.f;
    for (int n = tid; n < NN; n += 256) {
        float v = row[n];
        s += v; sq = fmaf(v, v, sq);
    }
    for (int o = 32; o > 0; o >>= 1) {
        s += __shfl_down(s, o);
        sq += __shfl_down(sq, o);
    }
    __shared__ float ws[4], wq[4];
    int lane = tid & 63, w = tid >> 6;
    if (lane == 0) { ws[w] = s; wq[w] = sq; }
    __syncthreads();
    if (tid == 0) {
        bn[c] = ws[0] + ws[1] + ws[2] + ws[3];
        bn[50 + c] = wq[0] + wq[1] + wq[2] + wq[3];
    }
}

__global__ void k_bnapply(const float* __restrict__ hrawT, const float* __restrict__ bn,
                          const float* __restrict__ gamma, const float* __restrict__ beta,
                          float* __restrict__ hT) {
    int idx = blockIdx.x * 256 + threadIdx.x;
    if (idx < D * NNP) {
        int c = idx / NNP, n = idx % NNP;
        float mean = bn[c] * (1.0f / NN);
        float var = bn[50 + c] * (1.0f / NN) - mean * mean;
        float v = gamma[c] * (hrawT[idx] - mean) * rsqrtf(var + EPS) + beta[c];
        hT[idx] = (n < NN) ? fmaxf(v, 0.f) : 0.f;
    }
}

__global__ void k_mlp(const float* __restrict__ hT, const int* __restrict__ perm,
                      const float* __restrict__ W1, const float* __restrict__ b1,
                      const float* __restrict__ W2, const float* __restrict__ b2,
                      float* __restrict__ out) {
    int n = blockIdx.x * 256 + threadIdx.x;
    if (n >= NN) return;
    float hv[50];
#pragma unroll
    for (int f = 0; f < 50; ++f) hv[f] = hT[(size_t)f * NNP + n];
    float s = b2[0];
    for (int o = 0; o < 25; ++o) {
        float a = b1[o];
        const float* w = W1 + o * 50;
#pragma unroll
        for (int f = 0; f < 50; ++f) a += w[f] * hv[f];
        s += W2[o] * fmaxf(a, 0.f);
    }
    out[perm[n]] = 1.0f / (1.0f + expf(-s));
}

// ------------------------------------------------------------------ launch
extern "C" void kernel_launch(void* const* d_in, const int* in_sizes, int n_in,
                              void* d_out, int out_size, void* d_ws, size_t ws_size,
                              hipStream_t stream) {
    const int* x = (const int*)d_in[0];
    const int* ei = (const int*)d_in[1];
    const int* src = ei;
    const int* dst = ei + NE;
    const float* emb   = (const float*)d_in[4];
    const float* preW  = (const float*)d_in[5];
    const float* preB  = (const float*)d_in[6];
    const float* postW = (const float*)d_in[7];
    const float* postB = (const float*)d_in[8];
    const float* linW  = (const float*)d_in[9];
    const float* linB  = (const float*)d_in[10];
    const float* gamma = (const float*)d_in[11];
    const float* beta  = (const float*)d_in[12];
    const float* W1 = (const float*)d_in[13];
    const float* b1 = (const float*)d_in[14];
    const float* W2 = (const float*)d_in[15];
    const float* b2 = (const float*)d_in[16];
    float* outp = (float*)d_out;

    char* wsp = (char*)d_ws;
    size_t off = 0;
    auto alloc = [&](size_t bytes) {
        void* p = wsp + off;
        off = (off + bytes + 1023) & ~(size_t)1023;
        return p;
    };
    int* deg     = (int*)alloc(NN * 4);
    int* cursor  = (int*)alloc(NN * 4);
    int* offs    = (int*)alloc((NN + 1) * 4);
    int* csr     = (int*)alloc(NE * 4);
    int* perm    = (int*)alloc(NN * 4);
    int* invp    = (int*)alloc(NN * 4);
    int* deg_r   = (int*)alloc(NN * 4);
    int* hist    = (int*)alloc(256 * 4);
    int* binbase = (int*)alloc(256 * 4);
    int* cursorb = (int*)alloc(256 * 4);
    float* bn    = (float*)alloc(512);     // [0:100) BN stats, [100] avg_log
    float* hT    = (float*)alloc((size_t)D * NNP * 4);
    float* hrawT = (float*)alloc((size_t)D * NNP * 4);
    float* yT    = (float*)alloc((size_t)D * NNP * 4);
    float* ai    = (float*)alloc((size_t)NN * ASTR * 4);
    float* aj    = (float*)alloc((size_t)NN * ASTR * 4);
    float* wT    = (float*)alloc((size_t)4 * TOWERS * 200 * 32 * 4);
    float* wxT   = (float*)alloc((size_t)4 * TOWERS * 50 * 16 * 4);
    float* aggT  = (float*)alloc((size_t)1000 * NNP * 4);
    (void)ws_size; (void)in_sizes; (void)n_in; (void)out_size;

    hipMemsetAsync(deg, 0, NN * 4, stream);
    hipMemsetAsync(cursor, 0, NN * 4, stream);
    hipMemsetAsync(hist, 0, 256 * 4, stream);
    hipMemsetAsync(cursorb, 0, 256 * 4, stream);
    hipMemsetAsync(bn, 0, 512, stream);

    k_deg<<<(NE + 255) / 256, 256, 0, stream>>>(dst, deg);
    k_hist<<<(NN + 255) / 256, 256, 0, stream>>>(deg, hist);
    k_binscan<<<1, 256, 0, stream>>>(hist, binbase);
    k_scatter<<<(NN + 255) / 256, 256, 0, stream>>>(deg, binbase, cursorb, perm, invp, deg_r);
    k_scan<<<1, 1024, 0, stream>>>(deg_r, offs);
    k_csr<<<(NE + 255) / 256, 256, 0, stream>>>(src, dst, offs, invp, cursor, csr);
    k_avglog<<<(NN + 255) / 256, 256, 0, stream>>>(deg, bn + 100);
    k_emb<<<(D * NNP + 255) / 256, 256, 0, stream>>>(x, emb, perm, hT);
    k_wt<<<(4 * TOWERS * 200 * 32 + 4 * TOWERS * 50 * 16 + 255) / 256, 256, 0, stream>>>(postW, wT, wxT);

    int aggblocks = 313 * 8;
    for (int l = 0; l < 4; ++l) {
        k_pre<<<313, 256, 0, stream>>>(hT, preW + l * TD * 100, ai, aj);
        k_agg<<<aggblocks, 512, 0, stream>>>(aj, offs, csr, ai, preB + l * TD, aggT);
        k_post<<<NGRP2 * TOWERS, 128, 0, stream>>>(hT, aggT, offs,
                                                   wT + l * TOWERS * 200 * 32,
                                                   wxT + l * TOWERS * 50 * 16,
                                                   postB + l * 50, bn + 100, yT);
        k_lin<<<NNP / 256, 256, 0, stream>>>(yT, linW + l * 2500, linB + l * 50, hrawT);
        k_bnstats<<<50, 256, 0, stream>>>(hrawT, bn);
        k_bnapply<<<(D * NNP + 255) / 256, 256, 0, stream>>>(hrawT, bn, gamma + l * 50,
                                                             beta + l * 50, hT);
    }
    k_mlp<<<(NN + 255) / 256, 256, 0, stream>>>(hT, perm, W1, b1, W2, b2, outp);
}

// Round 10
// 1016.952 us; speedup vs baseline: 1.4986x; 1.0993x over previous
//
#include <hip/hip_runtime.h>
#include <math.h>

#define NN 20000
#define NNP 20224   // padded to 158*128 (= 79*256)
#define NGRP2 158   // NNP/128
#define NE 320000
#define D 50
#define TOWERS 5
#define TD 250      // TOWERS*D
#define ASTR 256    // padded row stride for ai/aj
#define FOUT 10
#define EPS 1e-5f

// ------------------------------------------------------------------ setup
__global__ void k_deg(const int* __restrict__ dst, int* __restrict__ deg) {
    int e = blockIdx.x * 256 + threadIdx.x;
    if (e < NE) atomicAdd(&deg[dst[e]], 1);
}

__global__ void k_hist(const int* __restrict__ deg, int* __restrict__ hist) {
    int n = blockIdx.x * 256 + threadIdx.x;
    if (n < NN) atomicAdd(&hist[min(deg[n], 255)], 1);
}

__global__ void k_binscan(const int* __restrict__ hist, int* __restrict__ binbase) {
    __shared__ int b[256];
    int tid = threadIdx.x;
    b[tid] = hist[tid];
    __syncthreads();
    for (int off = 1; off < 256; off <<= 1) {
        int t = (tid >= off) ? b[tid - off] : 0;
        __syncthreads();
        b[tid] += t;
        __syncthreads();
    }
    binbase[tid] = b[tid] - hist[tid];   // exclusive
}

__global__ void k_scatter(const int* __restrict__ deg, const int* __restrict__ binbase,
                          int* __restrict__ cursorb, int* __restrict__ perm,
                          int* __restrict__ invp, int* __restrict__ deg_r) {
    int n = blockIdx.x * 256 + threadIdx.x;
    if (n < NN) {
        int d = min(deg[n], 255);
        int r = binbase[d] + atomicAdd(&cursorb[d], 1);
        perm[r] = n;
        invp[n] = r;
        deg_r[r] = deg[n];
    }
}

__global__ void k_scan(const int* __restrict__ deg, int* __restrict__ offs) {
    __shared__ int buf[1024];
    __shared__ int carry;
    int tid = threadIdx.x;
    if (tid == 0) carry = 0;
    __syncthreads();
    for (int base = 0; base < NN; base += 1024) {
        int i = base + tid;
        int v = (i < NN) ? deg[i] : 0;
        buf[tid] = v;
        __syncthreads();
        for (int off = 1; off < 1024; off <<= 1) {
            int t = (tid >= off) ? buf[tid - off] : 0;
            __syncthreads();
            buf[tid] += t;
            __syncthreads();
        }
        int excl = carry + buf[tid] - v;
        if (i < NN) offs[i] = excl;
        __syncthreads();
        if (tid == 0) carry += buf[1023];
        __syncthreads();
    }
    if (tid == 0) offs[NN] = carry;        // == NE
}

__global__ void k_csr(const int* __restrict__ src, const int* __restrict__ dst,
                      const int* __restrict__ offs, const int* __restrict__ invp,
                      int* __restrict__ cursor, int* __restrict__ csr_src) {
    int e = blockIdx.x * 256 + threadIdx.x;
    if (e < NE) {
        int rd = invp[dst[e]];
        int slot = atomicAdd(&cursor[rd], 1);
        csr_src[offs[rd] + slot] = invp[src[e]];
    }
}

__global__ void k_avglog(const int* __restrict__ deg, float* __restrict__ accum) {
    int n = blockIdx.x * 256 + threadIdx.x;
    float v = (n < NN) ? logf((float)deg[n] + 1.0f) : 0.0f;
    for (int o = 32; o > 0; o >>= 1) v += __shfl_down(v, o);
    __shared__ float wsum[4];
    int lane = threadIdx.x & 63, w = threadIdx.x >> 6;
    if (lane == 0) wsum[w] = v;
    __syncthreads();
    if (threadIdx.x == 0) atomicAdd(accum, wsum[0] + wsum[1] + wsum[2] + wsum[3]);
}

// embedding -> hT (feature-major, RANK space), zero pad columns
__global__ void k_emb(const int* __restrict__ x, const float* __restrict__ emb,
                      const int* __restrict__ perm, float* __restrict__ hT) {
    int idx = blockIdx.x * 256 + threadIdx.x;
    if (idx < D * NNP) {
        int c = idx / NNP, r = idx % NNP;
        hT[idx] = (r < NN) ? emb[x[perm[r]] * D + c] : 0.f;
    }
}

// transpose postW (all layers) into wT[l][t][200][32] (c = p*10+g, pad 30,31)
// and wxT[l][t][50][16] (c = g, pad 10..15) for scalar-broadcast GEMV.
__global__ void k_wt(const float* __restrict__ postW, float* __restrict__ wT,
                     float* __restrict__ wxT) {
    int idx = blockIdx.x * 256 + threadIdx.x;
    const int WTN = 4 * TOWERS * 200 * 32;
    if (idx < WTN) {
        int l = idx / (TOWERS * 200 * 32);
        int r = idx % (TOWERS * 200 * 32);
        int t = r / (200 * 32); r %= 200 * 32;
        int j = r / 32, c = r % 32;
        float v = 0.f;
        if (c < 30) {
            int p = c / 10, g = c % 10;
            v = postW[l * 32500 + (t * FOUT + g) * 650 + 50 + p * 200 + j];
        }
        wT[idx] = v;
    } else if (idx < WTN + 4 * TOWERS * 50 * 16) {
        int k = idx - WTN;
        int l = k / (TOWERS * 50 * 16);
        int r = k % (TOWERS * 50 * 16);
        int t = r / (50 * 16); r %= 50 * 16;
        int j = r / 16, c = r % 16;
        float v = 0.f;
        if (c < 10) v = postW[l * 32500 + (t * FOUT + c) * 650 + j];
        wxT[k] = v;
    }
}

// ------------------------------------------------------------- per layer
// pre-NN: 512 threads, thread o<250 -> ai row o, 250<=o<500 -> aj row o-250
// (50 W floats in registers each). x tile (32 nodes) in LDS as float4.
#define PRE_NT 32
__global__ __launch_bounds__(512) void k_pre(const float* __restrict__ hT,
                                             const float* __restrict__ preW, // [TD][2D]
                                             float* __restrict__ ai,
                                             float* __restrict__ aj) {
    __shared__ float xl[PRE_NT * 52];
    int n0 = blockIdx.x * PRE_NT;
    int tid = threadIdx.x;
    for (int k = tid; k < PRE_NT * 52; k += 512) {
        int nl = k & 31, f = k >> 5;
        xl[nl * 52 + f] = (f < 50) ? hT[(size_t)f * NNP + n0 + nl] : 0.f;
    }
    __syncthreads();
    int o = tid;
    if (o < 500) {
        int isj = (o >= 250) ? 1 : 0;
        int oo = o - isj * 250;
        const float* w0 = preW + oo * 100 + isj * 50;
        float w[52];
#pragma unroll
        for (int f = 0; f < 50; ++f) w[f] = w0[f];
        w[50] = 0.f; w[51] = 0.f;
        float* dstp = isj ? aj : ai;
        for (int nl = 0; nl < PRE_NT; ++nl) {
            const float4* xv = (const float4*)&xl[nl * 52];
            float a = 0.f;
#pragma unroll
            for (int j = 0; j < 13; ++j) {
                float4 x4 = xv[j];
                a = fmaf(x4.x, w[4 * j], a);
                a = fmaf(x4.y, w[4 * j + 1], a);
                a = fmaf(x4.z, w[4 * j + 2], a);
                a = fmaf(x4.w, w[4 * j + 3], a);
            }
            dstp[(size_t)(n0 + nl) * ASTR + oo] = a;
        }
    } else {                       // threads 500..511: zero pad cols 250..255
        int p = o - 500;
        int oo = 250 + (p % 6);
        float* dstp = (p < 6) ? ai : aj;
        for (int nl = 0; nl < PRE_NT; ++nl)
            dstp[(size_t)(n0 + nl) * ASTR + oo] = 0.f;
    }
}

// Edge aggregation, RANK space (degree-sorted -> no tail divergence).
// Grid = 313 nodeblocks x 8 chunks (chunk in low bits, XCD-pinned).
// Block 512 = 8 waves; wave = 16 nodes x 4 float4-cols (lane = g*4+q).
__global__ __launch_bounds__(512) void k_agg(
    const float* __restrict__ aj, const int* __restrict__ offs,
    const int* __restrict__ csr_src, const float* __restrict__ ai,
    const float* __restrict__ preB, float* __restrict__ aggT) {
    int chunk = blockIdx.x & 7;
    int nb = blockIdx.x >> 3;
    int tid = threadIdx.x;
    int wave = tid >> 6, lane = tid & 63;
    int g = lane >> 2, q = lane & 3;
    int r = nb * 64 + (wave >> 1) * 16 + g;
    int coloff = chunk * 8 + (wave & 1) * 4 + q;
    bool ok = r < NN;
    int e0 = 0, dg = 0;
    if (ok) { e0 = offs[r]; dg = offs[r + 1] - e0; }
    int mdeg = dg;
#pragma unroll
    for (int o = 4; o < 64; o <<= 1) mdeg = min(mdeg, __shfl_xor(mdeg, o));

    const float4* ajv = (const float4*)aj;
    float s1x = 0.f, s1y = 0.f, s1z = 0.f, s1w = 0.f;
    float s2x = 0.f, s2y = 0.f, s2z = 0.f, s2w = 0.f;
    float mnx = INFINITY, mny = INFINITY, mnz = INFINITY, mnw = INFINITY;
    float mxx = -INFINITY, mxy = -INFINITY, mxz = -INFINITY, mxw = -INFINITY;

    int it = 0;
    for (; it < mdeg; ++it) {                 // uniform part (sorted degrees)
        int s = csr_src[e0 + it];
        float4 v = ajv[((unsigned)s << 6) + coloff];
        s1x += v.x; s1y += v.y; s1z += v.z; s1w += v.w;
        s2x = fmaf(v.x, v.x, s2x); s2y = fmaf(v.y, v.y, s2y);
        s2z = fmaf(v.z, v.z, s2z); s2w = fmaf(v.w, v.w, s2w);
        mnx = fminf(mnx, v.x); mny = fminf(mny, v.y);
        mnz = fminf(mnz, v.z); mnw = fminf(mnw, v.w);
        mxx = fmaxf(mxx, v.x); mxy = fmaxf(mxy, v.y);
        mxz = fmaxf(mxz, v.z); mxw = fmaxf(mxw, v.w);
    }
    while (__any(it < dg)) {                  // tiny tail (bin boundaries)
        bool valid = it < dg;
        int s = csr_src[valid ? e0 + it : e0];
        float4 v = ajv[((unsigned)s << 6) + coloff];
        float zx = valid ? v.x : 0.f, zy = valid ? v.y : 0.f;
        float zz = valid ? v.z : 0.f, zw = valid ? v.w : 0.f;
        s1x += zx; s1y += zy; s1z += zz; s1w += zw;
        s2x = fmaf(zx, zx, s2x); s2y = fmaf(zy, zy, s2y);
        s2z = fmaf(zz, zz, s2z); s2w = fmaf(zw, zw, s2w);
        mnx = fminf(mnx, valid ? v.x : INFINITY);
        mny = fminf(mny, valid ? v.y : INFINITY);
        mnz = fminf(mnz, valid ? v.z : INFINITY);
        mnw = fminf(mnw, valid ? v.w : INFINITY);
        mxx = fmaxf(mxx, valid ? v.x : -INFINITY);
        mxy = fmaxf(mxy, valid ? v.y : -INFINITY);
        mxz = fmaxf(mxz, valid ? v.z : -INFINITY);
        mxw = fmaxf(mxw, valid ? v.w : -INFINITY);
        ++it;
    }

    if (ok) {
        float inv = 1.0f / (float)max(dg, 1);
        float m1a[4], mna[4], mxa[4], sda[4];
        m1a[0] = s1x * inv; m1a[1] = s1y * inv; m1a[2] = s1z * inv; m1a[3] = s1w * inv;
        sda[0] = sqrtf(fmaxf(s2x * inv - m1a[0] * m1a[0], 0.f) + EPS);
        sda[1] = sqrtf(fmaxf(s2y * inv - m1a[1] * m1a[1], 0.f) + EPS);
        sda[2] = sqrtf(fmaxf(s2z * inv - m1a[2] * m1a[2], 0.f) + EPS);
        sda[3] = sqrtf(fmaxf(s2w * inv - m1a[3] * m1a[3], 0.f) + EPS);
        mna[0] = mnx; mna[1] = mny; mna[2] = mnz; mna[3] = mnw;
        mxa[0] = mxx; mxa[1] = mxy; mxa[2] = mxz; mxa[3] = mxw;
        float4 aiv = ((const float4*)ai)[(size_t)r * 64 + coloff];
        float aia[4] = {aiv.x, aiv.y, aiv.z, aiv.w};
        int f0 = coloff * 4;
#pragma unroll
        for (int k = 0; k < 4; ++k) {
            int f = f0 + k;
            if (f < TD) {
                float base;
                if (dg > 0) {
                    base = aia[k] + preB[f];
                } else {
                    base = 0.f;
                    m1a[k] = 0.f; mna[k] = 0.f; mxa[k] = 0.f;
                }
                int t = f / 50, gg = f - t * 50;
                float* col = aggT + (size_t)(t * 200 + gg) * NNP + r;
                col[0]                 = m1a[k] + base;
                col[(size_t)50 * NNP]  = mna[k] + base;
                col[(size_t)100 * NNP] = mxa[k] + base;
                col[(size_t)150 * NNP] = sda[k];
            }
        }
    }
}

// post-NN: thread-per-node GEMV; weights via wave-uniform loads from
// pre-transposed wT/wxT. Grid = NGRP2 x TOWERS, block 128, no LDS.
__global__ __launch_bounds__(128) void k_post(
    const float* __restrict__ hT, const float* __restrict__ aggT,
    const int* __restrict__ offs,
    const float* __restrict__ wT,    // [T][200][32]
    const float* __restrict__ wxT,   // [T][50][16]
    const float* __restrict__ postB, // [50]
    const float* __restrict__ avg_accum, float* __restrict__ yT) {
    int t = blockIdx.x / NGRP2;
    int grp = blockIdx.x - t * NGRP2;
    int tid = threadIdx.x;
    int n = grp * 128 + tid;

    float acc[32];
#pragma unroll
    for (int i = 0; i < 32; ++i) acc[i] = 0.f;
    const float* aggcol = aggT + (size_t)(t * 200) * NNP + n;
    const float4* wv = (const float4*)(wT + t * 200 * 32);
#pragma unroll 2
    for (int j = 0; j < 200; ++j) {
        float a = aggcol[(size_t)j * NNP];
        float4 w0 = wv[j * 8 + 0], w1 = wv[j * 8 + 1], w2 = wv[j * 8 + 2],
               w3 = wv[j * 8 + 3], w4 = wv[j * 8 + 4], w5 = wv[j * 8 + 5],
               w6 = wv[j * 8 + 6], w7 = wv[j * 8 + 7];
        acc[0] = fmaf(a, w0.x, acc[0]);   acc[1] = fmaf(a, w0.y, acc[1]);
        acc[2] = fmaf(a, w0.z, acc[2]);   acc[3] = fmaf(a, w0.w, acc[3]);
        acc[4] = fmaf(a, w1.x, acc[4]);   acc[5] = fmaf(a, w1.y, acc[5]);
        acc[6] = fmaf(a, w1.z, acc[6]);   acc[7] = fmaf(a, w1.w, acc[7]);
        acc[8] = fmaf(a, w2.x, acc[8]);   acc[9] = fmaf(a, w2.y, acc[9]);
        acc[10] = fmaf(a, w2.z, acc[10]); acc[11] = fmaf(a, w2.w, acc[11]);
        acc[12] = fmaf(a, w3.x, acc[12]); acc[13] = fmaf(a, w3.y, acc[13]);
        acc[14] = fmaf(a, w3.z, acc[14]); acc[15] = fmaf(a, w3.w, acc[15]);
        acc[16] = fmaf(a, w4.x, acc[16]); acc[17] = fmaf(a, w4.y, acc[17]);
        acc[18] = fmaf(a, w4.z, acc[18]); acc[19] = fmaf(a, w4.w, acc[19]);
        acc[20] = fmaf(a, w5.x, acc[20]); acc[21] = fmaf(a, w5.y, acc[21]);
        acc[22] = fmaf(a, w5.z, acc[22]); acc[23] = fmaf(a, w5.w, acc[23]);
        acc[24] = fmaf(a, w6.x, acc[24]); acc[25] = fmaf(a, w6.y, acc[25]);
        acc[26] = fmaf(a, w6.z, acc[26]); acc[27] = fmaf(a, w6.w, acc[27]);
        acc[28] = fmaf(a, w7.x, acc[28]); acc[29] = fmaf(a, w7.y, acc[29]);
    }
    float xacc[10];
#pragma unroll
    for (int i = 0; i < 10; ++i) xacc[i] = 0.f;
    const float4* wxv = (const float4*)(wxT + t * 50 * 16);
#pragma unroll 2
    for (int j = 0; j < 50; ++j) {
        float a = hT[(size_t)j * NNP + n];
        float4 x0 = wxv[j * 4 + 0], x1 = wxv[j * 4 + 1], x2 = wxv[j * 4 + 2];
        xacc[0] = fmaf(a, x0.x, xacc[0]); xacc[1] = fmaf(a, x0.y, xacc[1]);
        xacc[2] = fmaf(a, x0.z, xacc[2]); xacc[3] = fmaf(a, x0.w, xacc[3]);
        xacc[4] = fmaf(a, x1.x, xacc[4]); xacc[5] = fmaf(a, x1.y, xacc[5]);
        xacc[6] = fmaf(a, x1.z, xacc[6]); xacc[7] = fmaf(a, x1.w, xacc[7]);
        xacc[8] = fmaf(a, x2.x, xacc[8]); xacc[9] = fmaf(a, x2.y, xacc[9]);
    }
    if (n < NN) {
        int dgn = offs[n + 1] - offs[n];
        float cnt = (float)max(dgn, 1);
        float sc = logf(cnt + 1.0f) / (avg_accum[0] * (1.0f / NN));
        float isc = 1.0f / sc;
#pragma unroll
        for (int g = 0; g < 10; ++g)
            yT[(size_t)(t * FOUT + g) * NNP + n] =
                postB[t * FOUT + g] + xacc[g] + acc[g] + sc * acc[10 + g] + isc * acc[20 + g];
    }
}

// 50x50 linear (pure), LDS-staged weights. 79 blocks x 256 threads.
__global__ __launch_bounds__(256) void k_lin(
    const float* __restrict__ yT, const float* __restrict__ linW,
    const float* __restrict__ linB, float* __restrict__ hrawT) {
    __shared__ float wl[2500];
    __shared__ float bl[50];
    int tid = threadIdx.x;
    int n = blockIdx.x * 256 + tid;
    for (int i = tid; i < 2500; i += 256) wl[i] = linW[i];
    if (tid < 50) bl[tid] = linB[tid];
    __syncthreads();
    float y[50];
#pragma unroll
    for (int q = 0; q < 50; ++q) y[q] = yT[(size_t)q * NNP + n];
    for (int c = 0; c < 50; ++c) {
        float a = bl[c];
        const float* w = wl + c * 50;
#pragma unroll
        for (int q = 0; q < 50; ++q) a = fmaf(w[q], y[q], a);
        hrawT[(size_t)c * NNP + n] = a;
    }
}

// BN stats: one block per channel, coalesced row reduce, direct write.
__global__ __launch_bounds__(256) void k_bnstats(const float* __restrict__ hrawT,
                                                 float* __restrict__ bn) {
    int c = blockIdx.x;
    int tid = threadIdx.x;
    const float* row = hrawT + (size_t)c * NNP;
    float s = 0.f, sq = 0.f;
    for (int n = tid; n < NN; n += 256) {
        float v = row[n];
        s += v; sq = fmaf(v, v, sq);
    }
    for (int o = 32; o > 0; o >>= 1) {
        s += __shfl_down(s, o);
        sq += __shfl_down(sq, o);
    }
    __shared__ float ws[4], wq[4];
    int lane = tid & 63, w = tid >> 6;
    if (lane == 0) { ws[w] = s; wq[w] = sq; }
    __syncthreads();
    if (tid == 0) {
        bn[c] = ws[0] + ws[1] + ws[2] + ws[3];
        bn[50 + c] = wq[0] + wq[1] + wq[2] + wq[3];
    }
}

__global__ void k_bnapply(const float* __restrict__ hrawT, const float* __restrict__ bn,
                          const float* __restrict__ gamma, const float* __restrict__ beta,
                          float* __restrict__ hT) {
    int idx = blockIdx.x * 256 + threadIdx.x;
    if (idx < D * NNP) {
        int c = idx / NNP, n = idx % NNP;
        float mean = bn[c] * (1.0f / NN);
        float var = bn[50 + c] * (1.0f / NN) - mean * mean;
        float v = gamma[c] * (hrawT[idx] - mean) * rsqrtf(var + EPS) + beta[c];
        hT[idx] = (n < NN) ? fmaxf(v, 0.f) : 0.f;
    }
}

__global__ void k_mlp(const float* __restrict__ hT, const int* __restrict__ perm,
                      const float* __restrict__ W1, const float* __restrict__ b1,
                      const float* __restrict__ W2, const float* __restrict__ b2,
                      float* __restrict__ out) {
    int n = blockIdx.x * 256 + threadIdx.x;
    if (n >= NN) return;
    float hv[50];
#pragma unroll
    for (int f = 0; f < 50; ++f) hv[f] = hT[(size_t)f * NNP + n];
    float s = b2[0];
    for (int o = 0; o < 25; ++o) {
        float a = b1[o];
        const float* w = W1 + o * 50;
#pragma unroll
        for (int f = 0; f < 50; ++f) a += w[f] * hv[f];
        s += W2[o] * fmaxf(a, 0.f);
    }
    out[perm[n]] = 1.0f / (1.0f + expf(-s));
}

// ------------------------------------------------------------------ launch
extern "C" void kernel_launch(void* const* d_in, const int* in_sizes, int n_in,
                              void* d_out, int out_size, void* d_ws, size_t ws_size,
                              hipStream_t stream) {
    const int* x = (const int*)d_in[0];
    const int* ei = (const int*)d_in[1];
    const int* src = ei;
    const int* dst = ei + NE;
    const float* emb   = (const float*)d_in[4];
    const float* preW  = (const float*)d_in[5];
    const float* preB  = (const float*)d_in[6];
    const float* postW = (const float*)d_in[7];
    const float* postB = (const float*)d_in[8];
    const float* linW  = (const float*)d_in[9];
    const float* linB  = (const float*)d_in[10];
    const float* gamma = (const float*)d_in[11];
    const float* beta  = (const float*)d_in[12];
    const float* W1 = (const float*)d_in[13];
    const float* b1 = (const float*)d_in[14];
    const float* W2 = (const float*)d_in[15];
    const float* b2 = (const float*)d_in[16];
    float* outp = (float*)d_out;

    char* wsp = (char*)d_ws;
    size_t off = 0;
    auto alloc = [&](size_t bytes) {
        void* p = wsp + off;
        off = (off + bytes + 1023) & ~(size_t)1023;
        return p;
    };
    int* deg     = (int*)alloc(NN * 4);
    int* cursor  = (int*)alloc(NN * 4);
    int* offs    = (int*)alloc((NN + 1) * 4);
    int* csr     = (int*)alloc(NE * 4);
    int* perm    = (int*)alloc(NN * 4);
    int* invp    = (int*)alloc(NN * 4);
    int* deg_r   = (int*)alloc(NN * 4);
    int* hist    = (int*)alloc(256 * 4);
    int* binbase = (int*)alloc(256 * 4);
    int* cursorb = (int*)alloc(256 * 4);
    float* bn    = (float*)alloc(512);     // [0:100) BN stats, [100] avg_log
    float* hT    = (float*)alloc((size_t)D * NNP * 4);
    float* hrawT = (float*)alloc((size_t)D * NNP * 4);
    float* yT    = (float*)alloc((size_t)D * NNP * 4);
    float* ai    = (float*)alloc((size_t)NN * ASTR * 4);
    float* aj    = (float*)alloc((size_t)NN * ASTR * 4);
    float* wT    = (float*)alloc((size_t)4 * TOWERS * 200 * 32 * 4);
    float* wxT   = (float*)alloc((size_t)4 * TOWERS * 50 * 16 * 4);
    float* aggT  = (float*)alloc((size_t)1000 * NNP * 4);
    (void)ws_size; (void)in_sizes; (void)n_in; (void)out_size;

    hipMemsetAsync(deg, 0, NN * 4, stream);
    hipMemsetAsync(cursor, 0, NN * 4, stream);
    hipMemsetAsync(hist, 0, 256 * 4, stream);
    hipMemsetAsync(cursorb, 0, 256 * 4, stream);
    hipMemsetAsync(bn, 0, 512, stream);

    k_deg<<<(NE + 255) / 256, 256, 0, stream>>>(dst, deg);
    k_hist<<<(NN + 255) / 256, 256, 0, stream>>>(deg, hist);
    k_binscan<<<1, 256, 0, stream>>>(hist, binbase);
    k_scatter<<<(NN + 255) / 256, 256, 0, stream>>>(deg, binbase, cursorb, perm, invp, deg_r);
    k_scan<<<1, 1024, 0, stream>>>(deg_r, offs);
    k_csr<<<(NE + 255) / 256, 256, 0, stream>>>(src, dst, offs, invp, cursor, csr);
    k_avglog<<<(NN + 255) / 256, 256, 0, stream>>>(deg, bn + 100);
    k_emb<<<(D * NNP + 255) / 256, 256, 0, stream>>>(x, emb, perm, hT);
    k_wt<<<(4 * TOWERS * 200 * 32 + 4 * TOWERS * 50 * 16 + 255) / 256, 256, 0, stream>>>(postW, wT, wxT);

    int aggblocks = 313 * 8;
    for (int l = 0; l < 4; ++l) {
        k_pre<<<NN / PRE_NT, 512, 0, stream>>>(hT, preW + l * TD * 100, ai, aj);
        k_agg<<<aggblocks, 512, 0, stream>>>(aj, offs, csr, ai, preB + l * TD, aggT);
        k_post<<<NGRP2 * TOWERS, 128, 0, stream>>>(hT, aggT, offs,
                                                   wT + l * TOWERS * 200 * 32,
                                                   wxT + l * TOWERS * 50 * 16,
                                                   postB + l * 50, bn + 100, yT);
        k_lin<<<NNP / 256, 256, 0, stream>>>(yT, linW + l * 2500, linB + l * 50, hrawT);
        k_bnstats<<<50, 256, 0, stream>>>(hrawT, bn);
        k_bnapply<<<(D * NNP + 255) / 256, 256, 0, stream>>>(hrawT, bn, gamma + l * 50,
                                                             beta + l * 50, hT);
    }
    k_mlp<<<(NN + 255) / 256, 256, 0, stream>>>(hT, perm, W1, b1, W2, b2, outp);
}

// Round 11
// 977.104 us; speedup vs baseline: 1.5598x; 1.0408x over previous
//
#include <hip/hip_runtime.h>
#include <hip/hip_fp16.h>
#include <math.h>

#define NN 20000
#define NNP 20224   // padded to 158*128 (= 79*256)
#define NGRP2 158   // NNP/128
#define NE 320000
#define D 50
#define TOWERS 5
#define TD 250      // TOWERS*D
#define ASTR 256    // padded row stride for ai/aj
#define FOUT 10
#define EPS 1e-5f

// ------------------------------------------------------------------ setup
__global__ void k_deg(const int* __restrict__ dst, int* __restrict__ deg) {
    int e = blockIdx.x * 256 + threadIdx.x;
    if (e < NE) atomicAdd(&deg[dst[e]], 1);
}

__global__ void k_hist(const int* __restrict__ deg, int* __restrict__ hist) {
    int n = blockIdx.x * 256 + threadIdx.x;
    if (n < NN) atomicAdd(&hist[min(deg[n], 255)], 1);
}

__global__ void k_binscan(const int* __restrict__ hist, int* __restrict__ binbase) {
    __shared__ int b[256];
    int tid = threadIdx.x;
    b[tid] = hist[tid];
    __syncthreads();
    for (int off = 1; off < 256; off <<= 1) {
        int t = (tid >= off) ? b[tid - off] : 0;
        __syncthreads();
        b[tid] += t;
        __syncthreads();
    }
    binbase[tid] = b[tid] - hist[tid];   // exclusive
}

__global__ void k_scatter(const int* __restrict__ deg, const int* __restrict__ binbase,
                          int* __restrict__ cursorb, int* __restrict__ perm,
                          int* __restrict__ invp, int* __restrict__ deg_r) {
    int n = blockIdx.x * 256 + threadIdx.x;
    if (n < NN) {
        int d = min(deg[n], 255);
        int r = binbase[d] + atomicAdd(&cursorb[d], 1);
        perm[r] = n;
        invp[n] = r;
        deg_r[r] = deg[n];
    }
}

__global__ void k_scan(const int* __restrict__ deg, int* __restrict__ offs) {
    __shared__ int buf[1024];
    __shared__ int carry;
    int tid = threadIdx.x;
    if (tid == 0) carry = 0;
    __syncthreads();
    for (int base = 0; base < NN; base += 1024) {
        int i = base + tid;
        int v = (i < NN) ? deg[i] : 0;
        buf[tid] = v;
        __syncthreads();
        for (int off = 1; off < 1024; off <<= 1) {
            int t = (tid >= off) ? buf[tid - off] : 0;
            __syncthreads();
            buf[tid] += t;
            __syncthreads();
        }
        int excl = carry + buf[tid] - v;
        if (i < NN) offs[i] = excl;
        __syncthreads();
        if (tid == 0) carry += buf[1023];
        __syncthreads();
    }
    if (tid == 0) offs[NN] = carry;        // == NE
}

__global__ void k_csr(const int* __restrict__ src, const int* __restrict__ dst,
                      const int* __restrict__ offs, const int* __restrict__ invp,
                      int* __restrict__ cursor, int* __restrict__ csr_src) {
    int e = blockIdx.x * 256 + threadIdx.x;
    if (e < NE) {
        int rd = invp[dst[e]];
        int slot = atomicAdd(&cursor[rd], 1);
        csr_src[offs[rd] + slot] = invp[src[e]];
    }
}

__global__ void k_avglog(const int* __restrict__ deg, float* __restrict__ accum) {
    int n = blockIdx.x * 256 + threadIdx.x;
    float v = (n < NN) ? logf((float)deg[n] + 1.0f) : 0.0f;
    for (int o = 32; o > 0; o >>= 1) v += __shfl_down(v, o);
    __shared__ float wsum[4];
    int lane = threadIdx.x & 63, w = threadIdx.x >> 6;
    if (lane == 0) wsum[w] = v;
    __syncthreads();
    if (threadIdx.x == 0) atomicAdd(accum, wsum[0] + wsum[1] + wsum[2] + wsum[3]);
}

// embedding -> hT (feature-major, RANK space), zero pad columns
__global__ void k_emb(const int* __restrict__ x, const float* __restrict__ emb,
                      const int* __restrict__ perm, float* __restrict__ hT) {
    int idx = blockIdx.x * 256 + threadIdx.x;
    if (idx < D * NNP) {
        int c = idx / NNP, r = idx % NNP;
        hT[idx] = (r < NN) ? emb[x[perm[r]] * D + c] : 0.f;
    }
}

// transpose postW (all layers) into wT[l][t][200][32] (c = p*10+g, pad 30,31)
// and wxT[l][t][50][16] (c = g, pad 10..15) for scalar-broadcast GEMV.
__global__ void k_wt(const float* __restrict__ postW, float* __restrict__ wT,
                     float* __restrict__ wxT) {
    int idx = blockIdx.x * 256 + threadIdx.x;
    const int WTN = 4 * TOWERS * 200 * 32;
    if (idx < WTN) {
        int l = idx / (TOWERS * 200 * 32);
        int r = idx % (TOWERS * 200 * 32);
        int t = r / (200 * 32); r %= 200 * 32;
        int j = r / 32, c = r % 32;
        float v = 0.f;
        if (c < 30) {
            int p = c / 10, g = c % 10;
            v = postW[l * 32500 + (t * FOUT + g) * 650 + 50 + p * 200 + j];
        }
        wT[idx] = v;
    } else if (idx < WTN + 4 * TOWERS * 50 * 16) {
        int k = idx - WTN;
        int l = k / (TOWERS * 50 * 16);
        int r = k % (TOWERS * 50 * 16);
        int t = r / (50 * 16); r %= 50 * 16;
        int j = r / 16, c = r % 16;
        float v = 0.f;
        if (c < 10) v = postW[l * 32500 + (t * FOUT + c) * 650 + j];
        wxT[k] = v;
    }
}

// ------------------------------------------------------------- per layer
// pre-NN: 512 threads, thread o<250 -> ai row o, 250<=o<500 -> aj row o-250
// (50 W floats in registers each). x tile (32 nodes) in LDS as float4.
#define PRE_NT 32
__global__ __launch_bounds__(512) void k_pre(const float* __restrict__ hT,
                                             const float* __restrict__ preW, // [TD][2D]
                                             float* __restrict__ ai,
                                             float* __restrict__ aj) {
    __shared__ float xl[PRE_NT * 52];
    int n0 = blockIdx.x * PRE_NT;
    int tid = threadIdx.x;
    for (int k = tid; k < PRE_NT * 52; k += 512) {
        int nl = k & 31, f = k >> 5;
        xl[nl * 52 + f] = (f < 50) ? hT[(size_t)f * NNP + n0 + nl] : 0.f;
    }
    __syncthreads();
    int o = tid;
    if (o < 500) {
        int isj = (o >= 250) ? 1 : 0;
        int oo = o - isj * 250;
        const float* w0 = preW + oo * 100 + isj * 50;
        float w[52];
#pragma unroll
        for (int f = 0; f < 50; ++f) w[f] = w0[f];
        w[50] = 0.f; w[51] = 0.f;
        float* dstp = isj ? aj : ai;
        for (int nl = 0; nl < PRE_NT; ++nl) {
            const float4* xv = (const float4*)&xl[nl * 52];
            float a = 0.f;
#pragma unroll
            for (int j = 0; j < 13; ++j) {
                float4 x4 = xv[j];
                a = fmaf(x4.x, w[4 * j], a);
                a = fmaf(x4.y, w[4 * j + 1], a);
                a = fmaf(x4.z, w[4 * j + 2], a);
                a = fmaf(x4.w, w[4 * j + 3], a);
            }
            dstp[(size_t)(n0 + nl) * ASTR + oo] = a;
        }
    } else {                       // threads 500..511: zero pad cols 250..255
        int p = o - 500;
        int oo = 250 + (p % 6);
        float* dstp = (p < 6) ? ai : aj;
        for (int nl = 0; nl < PRE_NT; ++nl)
            dstp[(size_t)(n0 + nl) * ASTR + oo] = 0.f;
    }
}

#define ACCV(v) do { \
    s1x += v.x; s1y += v.y; s1z += v.z; s1w += v.w; \
    s2x = fmaf(v.x, v.x, s2x); s2y = fmaf(v.y, v.y, s2y); \
    s2z = fmaf(v.z, v.z, s2z); s2w = fmaf(v.w, v.w, s2w); \
    mnx = fminf(mnx, v.x); mny = fminf(mny, v.y); \
    mnz = fminf(mnz, v.z); mnw = fminf(mnw, v.w); \
    mxx = fmaxf(mxx, v.x); mxy = fmaxf(mxy, v.y); \
    mxz = fmaxf(mxz, v.z); mxw = fmaxf(mxw, v.w); \
} while (0)

// Edge aggregation, RANK space (degree-sorted). Grid = 313 nodeblocks x 8
// chunks; chunk = low 3 bits (XCD-pinned); nodeblocks REVERSED so the
// high-degree blocks launch first (tail packing). 4-way edge unroll for MLP.
// Output aggT in fp16.
__global__ __launch_bounds__(512) void k_agg(
    const float* __restrict__ aj, const int* __restrict__ offs,
    const int* __restrict__ csr_src, const float* __restrict__ ai,
    const float* __restrict__ preB, __half* __restrict__ aggT) {
    int chunk = blockIdx.x & 7;
    int nb = (gridDim.x >> 3) - 1 - (blockIdx.x >> 3);   // reversed
    int tid = threadIdx.x;
    int wave = tid >> 6, lane = tid & 63;
    int g = lane >> 2, q = lane & 3;
    int r = nb * 64 + (wave >> 1) * 16 + g;
    int coloff = chunk * 8 + (wave & 1) * 4 + q;
    bool ok = r < NN;
    int e0 = 0, dg = 0;
    if (ok) { e0 = offs[r]; dg = offs[r + 1] - e0; }
    int mdeg = dg;
#pragma unroll
    for (int o = 4; o < 64; o <<= 1) mdeg = min(mdeg, __shfl_xor(mdeg, o));

    const float4* ajv = (const float4*)aj;
    float s1x = 0.f, s1y = 0.f, s1z = 0.f, s1w = 0.f;
    float s2x = 0.f, s2y = 0.f, s2z = 0.f, s2w = 0.f;
    float mnx = INFINITY, mny = INFINITY, mnz = INFINITY, mnw = INFINITY;
    float mxx = -INFINITY, mxy = -INFINITY, mxz = -INFINITY, mxw = -INFINITY;

    int it = 0;
    for (; it + 4 <= mdeg; it += 4) {         // uniform, 4 loads in flight
        int s0 = csr_src[e0 + it];
        int s1 = csr_src[e0 + it + 1];
        int s2 = csr_src[e0 + it + 2];
        int s3 = csr_src[e0 + it + 3];
        float4 v0 = ajv[((unsigned)s0 << 6) + coloff];
        float4 v1 = ajv[((unsigned)s1 << 6) + coloff];
        float4 v2 = ajv[((unsigned)s2 << 6) + coloff];
        float4 v3 = ajv[((unsigned)s3 << 6) + coloff];
        ACCV(v0); ACCV(v1); ACCV(v2); ACCV(v3);
    }
    for (; it < mdeg; ++it) {
        int s = csr_src[e0 + it];
        float4 v = ajv[((unsigned)s << 6) + coloff];
        ACCV(v);
    }
    while (__any(it < dg)) {                  // tiny tail (bin boundaries)
        bool valid = it < dg;
        int s = csr_src[valid ? e0 + it : e0];
        float4 v = ajv[((unsigned)s << 6) + coloff];
        float zx = valid ? v.x : 0.f, zy = valid ? v.y : 0.f;
        float zz = valid ? v.z : 0.f, zw = valid ? v.w : 0.f;
        s1x += zx; s1y += zy; s1z += zz; s1w += zw;
        s2x = fmaf(zx, zx, s2x); s2y = fmaf(zy, zy, s2y);
        s2z = fmaf(zz, zz, s2z); s2w = fmaf(zw, zw, s2w);
        mnx = fminf(mnx, valid ? v.x : INFINITY);
        mny = fminf(mny, valid ? v.y : INFINITY);
        mnz = fminf(mnz, valid ? v.z : INFINITY);
        mnw = fminf(mnw, valid ? v.w : INFINITY);
        mxx = fmaxf(mxx, valid ? v.x : -INFINITY);
        mxy = fmaxf(mxy, valid ? v.y : -INFINITY);
        mxz = fmaxf(mxz, valid ? v.z : -INFINITY);
        mxw = fmaxf(mxw, valid ? v.w : -INFINITY);
        ++it;
    }

    if (ok) {
        float inv = 1.0f / (float)max(dg, 1);
        float m1a[4], mna[4], mxa[4], sda[4];
        m1a[0] = s1x * inv; m1a[1] = s1y * inv; m1a[2] = s1z * inv; m1a[3] = s1w * inv;
        sda[0] = sqrtf(fmaxf(s2x * inv - m1a[0] * m1a[0], 0.f) + EPS);
        sda[1] = sqrtf(fmaxf(s2y * inv - m1a[1] * m1a[1], 0.f) + EPS);
        sda[2] = sqrtf(fmaxf(s2z * inv - m1a[2] * m1a[2], 0.f) + EPS);
        sda[3] = sqrtf(fmaxf(s2w * inv - m1a[3] * m1a[3], 0.f) + EPS);
        mna[0] = mnx; mna[1] = mny; mna[2] = mnz; mna[3] = mnw;
        mxa[0] = mxx; mxa[1] = mxy; mxa[2] = mxz; mxa[3] = mxw;
        float4 aiv = ((const float4*)ai)[(size_t)r * 64 + coloff];
        float aia[4] = {aiv.x, aiv.y, aiv.z, aiv.w};
        int f0 = coloff * 4;
#pragma unroll
        for (int k = 0; k < 4; ++k) {
            int f = f0 + k;
            if (f < TD) {
                float base;
                if (dg > 0) {
                    base = aia[k] + preB[f];
                } else {
                    base = 0.f;
                    m1a[k] = 0.f; mna[k] = 0.f; mxa[k] = 0.f;
                }
                int t = f / 50, gg = f - t * 50;
                __half* col = aggT + (size_t)(t * 200 + gg) * NNP + r;
                col[0]                 = __float2half(m1a[k] + base);
                col[(size_t)50 * NNP]  = __float2half(mna[k] + base);
                col[(size_t)100 * NNP] = __float2half(mxa[k] + base);
                col[(size_t)150 * NNP] = __float2half(sda[k]);
            }
        }
    }
}

// post-NN: thread-per-node GEMV over fp16 aggT; weights via wave-uniform
// loads from pre-transposed wT/wxT. Grid = NGRP2 x TOWERS, block 128.
__global__ __launch_bounds__(128) void k_post(
    const float* __restrict__ hT, const __half* __restrict__ aggT,
    const int* __restrict__ offs,
    const float* __restrict__ wT,    // [T][200][32]
    const float* __restrict__ wxT,   // [T][50][16]
    const float* __restrict__ postB, // [50]
    const float* __restrict__ avg_accum, float* __restrict__ yT) {
    int t = blockIdx.x / NGRP2;
    int grp = blockIdx.x - t * NGRP2;
    int tid = threadIdx.x;
    int n = grp * 128 + tid;

    float acc[32];
#pragma unroll
    for (int i = 0; i < 32; ++i) acc[i] = 0.f;
    const __half* aggcol = aggT + (size_t)(t * 200) * NNP + n;
    const float4* wv = (const float4*)(wT + t * 200 * 32);
#pragma unroll 2
    for (int j = 0; j < 200; ++j) {
        float a = __half2float(aggcol[(size_t)j * NNP]);
        float4 w0 = wv[j * 8 + 0], w1 = wv[j * 8 + 1], w2 = wv[j * 8 + 2],
               w3 = wv[j * 8 + 3], w4 = wv[j * 8 + 4], w5 = wv[j * 8 + 5],
               w6 = wv[j * 8 + 6], w7 = wv[j * 8 + 7];
        acc[0] = fmaf(a, w0.x, acc[0]);   acc[1] = fmaf(a, w0.y, acc[1]);
        acc[2] = fmaf(a, w0.z, acc[2]);   acc[3] = fmaf(a, w0.w, acc[3]);
        acc[4] = fmaf(a, w1.x, acc[4]);   acc[5] = fmaf(a, w1.y, acc[5]);
        acc[6] = fmaf(a, w1.z, acc[6]);   acc[7] = fmaf(a, w1.w, acc[7]);
        acc[8] = fmaf(a, w2.x, acc[8]);   acc[9] = fmaf(a, w2.y, acc[9]);
        acc[10] = fmaf(a, w2.z, acc[10]); acc[11] = fmaf(a, w2.w, acc[11]);
        acc[12] = fmaf(a, w3.x, acc[12]); acc[13] = fmaf(a, w3.y, acc[13]);
        acc[14] = fmaf(a, w3.z, acc[14]); acc[15] = fmaf(a, w3.w, acc[15]);
        acc[16] = fmaf(a, w4.x, acc[16]); acc[17] = fmaf(a, w4.y, acc[17]);
        acc[18] = fmaf(a, w4.z, acc[18]); acc[19] = fmaf(a, w4.w, acc[19]);
        acc[20] = fmaf(a, w5.x, acc[20]); acc[21] = fmaf(a, w5.y, acc[21]);
        acc[22] = fmaf(a, w5.z, acc[22]); acc[23] = fmaf(a, w5.w, acc[23]);
        acc[24] = fmaf(a, w6.x, acc[24]); acc[25] = fmaf(a, w6.y, acc[25]);
        acc[26] = fmaf(a, w6.z, acc[26]); acc[27] = fmaf(a, w6.w, acc[27]);
        acc[28] = fmaf(a, w7.x, acc[28]); acc[29] = fmaf(a, w7.y, acc[29]);
    }
    float xacc[10];
#pragma unroll
    for (int i = 0; i < 10; ++i) xacc[i] = 0.f;
    const float4* wxv = (const float4*)(wxT + t * 50 * 16);
#pragma unroll 2
    for (int j = 0; j < 50; ++j) {
        float a = hT[(size_t)j * NNP + n];
        float4 x0 = wxv[j * 4 + 0], x1 = wxv[j * 4 + 1], x2 = wxv[j * 4 + 2];
        xacc[0] = fmaf(a, x0.x, xacc[0]); xacc[1] = fmaf(a, x0.y, xacc[1]);
        xacc[2] = fmaf(a, x0.z, xacc[2]); xacc[3] = fmaf(a, x0.w, xacc[3]);
        xacc[4] = fmaf(a, x1.x, xacc[4]); xacc[5] = fmaf(a, x1.y, xacc[5]);
        xacc[6] = fmaf(a, x1.z, xacc[6]); xacc[7] = fmaf(a, x1.w, xacc[7]);
        xacc[8] = fmaf(a, x2.x, xacc[8]); xacc[9] = fmaf(a, x2.y, xacc[9]);
    }
    if (n < NN) {
        int dgn = offs[n + 1] - offs[n];
        float cnt = (float)max(dgn, 1);
        float sc = logf(cnt + 1.0f) / (avg_accum[0] * (1.0f / NN));
        float isc = 1.0f / sc;
#pragma unroll
        for (int g = 0; g < 10; ++g)
            yT[(size_t)(t * FOUT + g) * NNP + n] =
                postB[t * FOUT + g] + xacc[g] + acc[g] + sc * acc[10 + g] + isc * acc[20 + g];
    }
}

// 50x50 linear (pure), LDS-staged weights. 79 blocks x 256 threads.
__global__ __launch_bounds__(256) void k_lin(
    const float* __restrict__ yT, const float* __restrict__ linW,
    const float* __restrict__ linB, float* __restrict__ hrawT) {
    __shared__ float wl[2500];
    __shared__ float bl[50];
    int tid = threadIdx.x;
    int n = blockIdx.x * 256 + tid;
    for (int i = tid; i < 2500; i += 256) wl[i] = linW[i];
    if (tid < 50) bl[tid] = linB[tid];
    __syncthreads();
    float y[50];
#pragma unroll
    for (int q = 0; q < 50; ++q) y[q] = yT[(size_t)q * NNP + n];
    for (int c = 0; c < 50; ++c) {
        float a = bl[c];
        const float* w = wl + c * 50;
#pragma unroll
        for (int q = 0; q < 50; ++q) a = fmaf(w[q], y[q], a);
        hrawT[(size_t)c * NNP + n] = a;
    }
}

// BN stats: one block per channel, coalesced row reduce, direct write.
__global__ __launch_bounds__(256) void k_bnstats(const float* __restrict__ hrawT,
                                                 float* __restrict__ bn) {
    int c = blockIdx.x;
    int tid = threadIdx.x;
    const float* row = hrawT + (size_t)c * NNP;
    float s = 0.f, sq = 0.f;
    for (int n = tid; n < NN; n += 256) {
        float v = row[n];
        s += v; sq = fmaf(v, v, sq);
    }
    for (int o = 32; o > 0; o >>= 1) {
        s += __shfl_down(s, o);
        sq += __shfl_down(sq, o);
    }
    __shared__ float ws[4], wq[4];
    int lane = tid & 63, w = tid >> 6;
    if (lane == 0) { ws[w] = s; wq[w] = sq; }
    __syncthreads();
    if (tid == 0) {
        bn[c] = ws[0] + ws[1] + ws[2] + ws[3];
        bn[50 + c] = wq[0] + wq[1] + wq[2] + wq[3];
    }
}

__global__ void k_bnapply(const float* __restrict__ hrawT, const float* __restrict__ bn,
                          const float* __restrict__ gamma, const float* __restrict__ beta,
                          float* __restrict__ hT) {
    int idx = blockIdx.x * 256 + threadIdx.x;
    if (idx < D * NNP) {
        int c = idx / NNP, n = idx % NNP;
        float mean = bn[c] * (1.0f / NN);
        float var = bn[50 + c] * (1.0f / NN) - mean * mean;
        float v = gamma[c] * (hrawT[idx] - mean) * rsqrtf(var + EPS) + beta[c];
        hT[idx] = (n < NN) ? fmaxf(v, 0.f) : 0.f;
    }
}

__global__ void k_mlp(const float* __restrict__ hT, const int* __restrict__ perm,
                      const float* __restrict__ W1, const float* __restrict__ b1,
                      const float* __restrict__ W2, const float* __restrict__ b2,
                      float* __restrict__ out) {
    int n = blockIdx.x * 256 + threadIdx.x;
    if (n >= NN) return;
    float hv[50];
#pragma unroll
    for (int f = 0; f < 50; ++f) hv[f] = hT[(size_t)f * NNP + n];
    float s = b2[0];
    for (int o = 0; o < 25; ++o) {
        float a = b1[o];
        const float* w = W1 + o * 50;
#pragma unroll
        for (int f = 0; f < 50; ++f) a += w[f] * hv[f];
        s += W2[o] * fmaxf(a, 0.f);
    }
    out[perm[n]] = 1.0f / (1.0f + expf(-s));
}

// ------------------------------------------------------------------ launch
extern "C" void kernel_launch(void* const* d_in, const int* in_sizes, int n_in,
                              void* d_out, int out_size, void* d_ws, size_t ws_size,
                              hipStream_t stream) {
    const int* x = (const int*)d_in[0];
    const int* ei = (const int*)d_in[1];
    const int* src = ei;
    const int* dst = ei + NE;
    const float* emb   = (const float*)d_in[4];
    const float* preW  = (const float*)d_in[5];
    const float* preB  = (const float*)d_in[6];
    const float* postW = (const float*)d_in[7];
    const float* postB = (const float*)d_in[8];
    const float* linW  = (const float*)d_in[9];
    const float* linB  = (const float*)d_in[10];
    const float* gamma = (const float*)d_in[11];
    const float* beta  = (const float*)d_in[12];
    const float* W1 = (const float*)d_in[13];
    const float* b1 = (const float*)d_in[14];
    const float* W2 = (const float*)d_in[15];
    const float* b2 = (const float*)d_in[16];
    float* outp = (float*)d_out;

    char* wsp = (char*)d_ws;
    size_t off = 0;
    auto alloc = [&](size_t bytes) {
        void* p = wsp + off;
        off = (off + bytes + 1023) & ~(size_t)1023;
        return p;
    };
    int* deg     = (int*)alloc(NN * 4);
    int* cursor  = (int*)alloc(NN * 4);
    int* offs    = (int*)alloc((NN + 1) * 4);
    int* csr     = (int*)alloc(NE * 4);
    int* perm    = (int*)alloc(NN * 4);
    int* invp    = (int*)alloc(NN * 4);
    int* deg_r   = (int*)alloc(NN * 4);
    int* hist    = (int*)alloc(256 * 4);
    int* binbase = (int*)alloc(256 * 4);
    int* cursorb = (int*)alloc(256 * 4);
    float* bn    = (float*)alloc(512);     // [0:100) BN stats, [100] avg_log
    float* hT    = (float*)alloc((size_t)D * NNP * 4);
    float* hrawT = (float*)alloc((size_t)D * NNP * 4);
    float* yT    = (float*)alloc((size_t)D * NNP * 4);
    float* ai    = (float*)alloc((size_t)NN * ASTR * 4);
    float* aj    = (float*)alloc((size_t)NN * ASTR * 4);
    float* wT    = (float*)alloc((size_t)4 * TOWERS * 200 * 32 * 4);
    float* wxT   = (float*)alloc((size_t)4 * TOWERS * 50 * 16 * 4);
    __half* aggT = (__half*)alloc((size_t)1000 * NNP * 2);  // fp16 stats+base
    (void)ws_size; (void)in_sizes; (void)n_in; (void)out_size;

    hipMemsetAsync(deg, 0, NN * 4, stream);
    hipMemsetAsync(cursor, 0, NN * 4, stream);
    hipMemsetAsync(hist, 0, 256 * 4, stream);
    hipMemsetAsync(cursorb, 0, 256 * 4, stream);
    hipMemsetAsync(bn, 0, 512, stream);

    k_deg<<<(NE + 255) / 256, 256, 0, stream>>>(dst, deg);
    k_hist<<<(NN + 255) / 256, 256, 0, stream>>>(deg, hist);
    k_binscan<<<1, 256, 0, stream>>>(hist, binbase);
    k_scatter<<<(NN + 255) / 256, 256, 0, stream>>>(deg, binbase, cursorb, perm, invp, deg_r);
    k_scan<<<1, 1024, 0, stream>>>(deg_r, offs);
    k_csr<<<(NE + 255) / 256, 256, 0, stream>>>(src, dst, offs, invp, cursor, csr);
    k_avglog<<<(NN + 255) / 256, 256, 0, stream>>>(deg, bn + 100);
    k_emb<<<(D * NNP + 255) / 256, 256, 0, stream>>>(x, emb, perm, hT);
    k_wt<<<(4 * TOWERS * 200 * 32 + 4 * TOWERS * 50 * 16 + 255) / 256, 256, 0, stream>>>(postW, wT, wxT);

    int aggblocks = 313 * 8;
    for (int l = 0; l < 4; ++l) {
        k_pre<<<NN / PRE_NT, 512, 0, stream>>>(hT, preW + l * TD * 100, ai, aj);
        k_agg<<<aggblocks, 512, 0, stream>>>(aj, offs, csr, ai, preB + l * TD, aggT);
        k_post<<<NGRP2 * TOWERS, 128, 0, stream>>>(hT, aggT, offs,
                                                   wT + l * TOWERS * 200 * 32,
                                                   wxT + l * TOWERS * 50 * 16,
                                                   postB + l * 50, bn + 100, yT);
        k_lin<<<NNP / 256, 256, 0, stream>>>(yT, linW + l * 2500, linB + l * 50, hrawT);
        k_bnstats<<<50, 256, 0, stream>>>(hrawT, bn);
        k_bnapply<<<(D * NNP + 255) / 256, 256, 0, stream>>>(hrawT, bn, gamma + l * 50,
                                                             beta + l * 50, hT);
    }
    k_mlp<<<(NN + 255) / 256, 256, 0, stream>>>(hT, perm, W1, b1, W2, b2, outp);
}

// Round 12
// 855.963 us; speedup vs baseline: 1.7805x; 1.1415x over previous
//
#include <hip/hip_runtime.h>
#include <hip/hip_fp16.h>
#include <math.h>

#define NN 20000
#define NNP 20224   // padded to 158*128 (= 79*256)
#define NGRP2 158   // NNP/128
#define NE 320000
#define D 50
#define TOWERS 5
#define TD 250      // TOWERS*D
#define ASTR 256    // padded row stride for ai/aj
#define FOUT 10
#define EPS 1e-5f

// ------------------------------------------------------------------ setup
__global__ void k_deg(const int* __restrict__ dst, int* __restrict__ deg) {
    int e = blockIdx.x * 256 + threadIdx.x;
    if (e < NE) atomicAdd(&deg[dst[e]], 1);
}

__global__ void k_hist(const int* __restrict__ deg, int* __restrict__ hist) {
    int n = blockIdx.x * 256 + threadIdx.x;
    if (n < NN) atomicAdd(&hist[min(deg[n], 255)], 1);
}

__global__ void k_binscan(const int* __restrict__ hist, int* __restrict__ binbase) {
    __shared__ int b[256];
    int tid = threadIdx.x;
    b[tid] = hist[tid];
    __syncthreads();
    for (int off = 1; off < 256; off <<= 1) {
        int t = (tid >= off) ? b[tid - off] : 0;
        __syncthreads();
        b[tid] += t;
        __syncthreads();
    }
    binbase[tid] = b[tid] - hist[tid];   // exclusive
}

// LDS-histogram scatter: block counts bins locally, reserves one global
// range per (bin, block) -> 256 distributed atomics/block, no same-address
// pileup (the naive version serialized ~2000 atomics on the mode bin).
__global__ __launch_bounds__(256) void k_scatter(
    const int* __restrict__ deg, const int* __restrict__ binbase,
    int* __restrict__ cursorb, int* __restrict__ perm,
    int* __restrict__ invp, int* __restrict__ deg_r) {
    __shared__ int lh[256];
    __shared__ int lbase[256];
    int tid = threadIdx.x;
    lh[tid] = 0;
    __syncthreads();
    int n = blockIdx.x * 256 + tid;
    int d = 0, slot = 0;
    bool ok = n < NN;
    if (ok) {
        d = min(deg[n], 255);
        slot = atomicAdd(&lh[d], 1);
    }
    __syncthreads();
    if (lh[tid] > 0) lbase[tid] = atomicAdd(&cursorb[tid], lh[tid]);
    __syncthreads();
    if (ok) {
        int r = binbase[d] + lbase[d] + slot;
        perm[r] = n;
        invp[n] = r;
        deg_r[r] = deg[n];
    }
}

__global__ void k_scan(const int* __restrict__ deg, int* __restrict__ offs) {
    __shared__ int buf[1024];
    __shared__ int carry;
    int tid = threadIdx.x;
    if (tid == 0) carry = 0;
    __syncthreads();
    for (int base = 0; base < NN; base += 1024) {
        int i = base + tid;
        int v = (i < NN) ? deg[i] : 0;
        buf[tid] = v;
        __syncthreads();
        for (int off = 1; off < 1024; off <<= 1) {
            int t = (tid >= off) ? buf[tid - off] : 0;
            __syncthreads();
            buf[tid] += t;
            __syncthreads();
        }
        int excl = carry + buf[tid] - v;
        if (i < NN) offs[i] = excl;
        __syncthreads();
        if (tid == 0) carry += buf[1023];
        __syncthreads();
    }
    if (tid == 0) offs[NN] = carry;        // == NE
}

__global__ void k_csr(const int* __restrict__ src, const int* __restrict__ dst,
                      const int* __restrict__ offs, const int* __restrict__ invp,
                      int* __restrict__ cursor, int* __restrict__ csr_src) {
    int e = blockIdx.x * 256 + threadIdx.x;
    if (e < NE) {
        int rd = invp[dst[e]];
        int slot = atomicAdd(&cursor[rd], 1);
        csr_src[offs[rd] + slot] = invp[src[e]];
    }
}

__global__ void k_avglog(const int* __restrict__ deg, float* __restrict__ accum) {
    int n = blockIdx.x * 256 + threadIdx.x;
    float v = (n < NN) ? logf((float)deg[n] + 1.0f) : 0.0f;
    for (int o = 32; o > 0; o >>= 1) v += __shfl_down(v, o);
    __shared__ float wsum[4];
    int lane = threadIdx.x & 63, w = threadIdx.x >> 6;
    if (lane == 0) wsum[w] = v;
    __syncthreads();
    if (threadIdx.x == 0) atomicAdd(accum, wsum[0] + wsum[1] + wsum[2] + wsum[3]);
}

// embedding -> hT (feature-major, RANK space), zero pad columns
__global__ void k_emb(const int* __restrict__ x, const float* __restrict__ emb,
                      const int* __restrict__ perm, float* __restrict__ hT) {
    int idx = blockIdx.x * 256 + threadIdx.x;
    if (idx < D * NNP) {
        int c = idx / NNP, r = idx % NNP;
        hT[idx] = (r < NN) ? emb[x[perm[r]] * D + c] : 0.f;
    }
}

// transpose postW (all layers) into wT[l][t][200][32] (c = p*10+g, pad 30,31)
// and wxT[l][t][50][16] (c = g, pad 10..15) for scalar-broadcast GEMV.
__global__ void k_wt(const float* __restrict__ postW, float* __restrict__ wT,
                     float* __restrict__ wxT) {
    int idx = blockIdx.x * 256 + threadIdx.x;
    const int WTN = 4 * TOWERS * 200 * 32;
    if (idx < WTN) {
        int l = idx / (TOWERS * 200 * 32);
        int r = idx % (TOWERS * 200 * 32);
        int t = r / (200 * 32); r %= 200 * 32;
        int j = r / 32, c = r % 32;
        float v = 0.f;
        if (c < 30) {
            int p = c / 10, g = c % 10;
            v = postW[l * 32500 + (t * FOUT + g) * 650 + 50 + p * 200 + j];
        }
        wT[idx] = v;
    } else if (idx < WTN + 4 * TOWERS * 50 * 16) {
        int k = idx - WTN;
        int l = k / (TOWERS * 50 * 16);
        int r = k % (TOWERS * 50 * 16);
        int t = r / (50 * 16); r %= 50 * 16;
        int j = r / 16, c = r % 16;
        float v = 0.f;
        if (c < 10) v = postW[l * 32500 + (t * FOUT + c) * 650 + j];
        wxT[k] = v;
    }
}

// ------------------------------------------------------------- per layer
// pre-NN: 512 threads, thread o<250 -> ai row o, 250<=o<500 -> aj row o-250
// (50 W floats in registers each). x tile (32 nodes) in LDS as float4.
#define PRE_NT 32
__global__ __launch_bounds__(512) void k_pre(const float* __restrict__ hT,
                                             const float* __restrict__ preW, // [TD][2D]
                                             float* __restrict__ ai,
                                             float* __restrict__ aj) {
    __shared__ float xl[PRE_NT * 52];
    int n0 = blockIdx.x * PRE_NT;
    int tid = threadIdx.x;
    for (int k = tid; k < PRE_NT * 52; k += 512) {
        int nl = k & 31, f = k >> 5;
        xl[nl * 52 + f] = (f < 50) ? hT[(size_t)f * NNP + n0 + nl] : 0.f;
    }
    __syncthreads();
    int o = tid;
    if (o < 500) {
        int isj = (o >= 250) ? 1 : 0;
        int oo = o - isj * 250;
        const float* w0 = preW + oo * 100 + isj * 50;
        float w[52];
#pragma unroll
        for (int f = 0; f < 50; ++f) w[f] = w0[f];
        w[50] = 0.f; w[51] = 0.f;
        float* dstp = isj ? aj : ai;
        for (int nl = 0; nl < PRE_NT; ++nl) {
            const float4* xv = (const float4*)&xl[nl * 52];
            float a = 0.f;
#pragma unroll
            for (int j = 0; j < 13; ++j) {
                float4 x4 = xv[j];
                a = fmaf(x4.x, w[4 * j], a);
                a = fmaf(x4.y, w[4 * j + 1], a);
                a = fmaf(x4.z, w[4 * j + 2], a);
                a = fmaf(x4.w, w[4 * j + 3], a);
            }
            dstp[(size_t)(n0 + nl) * ASTR + oo] = a;
        }
    } else {                       // threads 500..511: zero pad cols 250..255
        int p = o - 500;
        int oo = 250 + (p % 6);
        float* dstp = (p < 6) ? ai : aj;
        for (int nl = 0; nl < PRE_NT; ++nl)
            dstp[(size_t)(n0 + nl) * ASTR + oo] = 0.f;
    }
}

#define ACCV(v) do { \
    s1x += v.x; s1y += v.y; s1z += v.z; s1w += v.w; \
    s2x = fmaf(v.x, v.x, s2x); s2y = fmaf(v.y, v.y, s2y); \
    s2z = fmaf(v.z, v.z, s2z); s2w = fmaf(v.w, v.w, s2w); \
    mnx = fminf(mnx, v.x); mny = fminf(mny, v.y); \
    mnz = fminf(mnz, v.z); mnw = fminf(mnw, v.w); \
    mxx = fmaxf(mxx, v.x); mxy = fmaxf(mxy, v.y); \
    mxz = fmaxf(mxz, v.z); mxw = fmaxf(mxw, v.w); \
} while (0)

// Edge aggregation, RANK space (degree-sorted). Grid = 313 nodeblocks x 8
// chunks; chunk = low 3 bits (XCD-pinned); nodeblocks REVERSED so the
// high-degree blocks launch first (tail packing). fp16 output.
__global__ __launch_bounds__(512) void k_agg(
    const float* __restrict__ aj, const int* __restrict__ offs,
    const int* __restrict__ csr_src, const float* __restrict__ ai,
    const float* __restrict__ preB, __half* __restrict__ aggT) {
    int chunk = blockIdx.x & 7;
    int nb = (gridDim.x >> 3) - 1 - (blockIdx.x >> 3);   // reversed
    int tid = threadIdx.x;
    int wave = tid >> 6, lane = tid & 63;
    int g = lane >> 2, q = lane & 3;
    int r = nb * 64 + (wave >> 1) * 16 + g;
    int coloff = chunk * 8 + (wave & 1) * 4 + q;
    bool ok = r < NN;
    int e0 = 0, dg = 0;
    if (ok) { e0 = offs[r]; dg = offs[r + 1] - e0; }
    int mdeg = dg;
#pragma unroll
    for (int o = 4; o < 64; o <<= 1) mdeg = min(mdeg, __shfl_xor(mdeg, o));

    const float4* ajv = (const float4*)aj;
    float s1x = 0.f, s1y = 0.f, s1z = 0.f, s1w = 0.f;
    float s2x = 0.f, s2y = 0.f, s2z = 0.f, s2w = 0.f;
    float mnx = INFINITY, mny = INFINITY, mnz = INFINITY, mnw = INFINITY;
    float mxx = -INFINITY, mxy = -INFINITY, mxz = -INFINITY, mxw = -INFINITY;

    int it = 0;
    for (; it + 4 <= mdeg; it += 4) {         // uniform, 4 loads in flight
        int s0 = csr_src[e0 + it];
        int s1 = csr_src[e0 + it + 1];
        int s2 = csr_src[e0 + it + 2];
        int s3 = csr_src[e0 + it + 3];
        float4 v0 = ajv[((unsigned)s0 << 6) + coloff];
        float4 v1 = ajv[((unsigned)s1 << 6) + coloff];
        float4 v2 = ajv[((unsigned)s2 << 6) + coloff];
        float4 v3 = ajv[((unsigned)s3 << 6) + coloff];
        ACCV(v0); ACCV(v1); ACCV(v2); ACCV(v3);
    }
    for (; it < mdeg; ++it) {
        int s = csr_src[e0 + it];
        float4 v = ajv[((unsigned)s << 6) + coloff];
        ACCV(v);
    }
    while (__any(it < dg)) {                  // tiny tail (bin boundaries)
        bool valid = it < dg;
        int s = csr_src[valid ? e0 + it : e0];
        float4 v = ajv[((unsigned)s << 6) + coloff];
        float zx = valid ? v.x : 0.f, zy = valid ? v.y : 0.f;
        float zz = valid ? v.z : 0.f, zw = valid ? v.w : 0.f;
        s1x += zx; s1y += zy; s1z += zz; s1w += zw;
        s2x = fmaf(zx, zx, s2x); s2y = fmaf(zy, zy, s2y);
        s2z = fmaf(zz, zz, s2z); s2w = fmaf(zw, zw, s2w);
        mnx = fminf(mnx, valid ? v.x : INFINITY);
        mny = fminf(mny, valid ? v.y : INFINITY);
        mnz = fminf(mnz, valid ? v.z : INFINITY);
        mnw = fminf(mnw, valid ? v.w : INFINITY);
        mxx = fmaxf(mxx, valid ? v.x : -INFINITY);
        mxy = fmaxf(mxy, valid ? v.y : -INFINITY);
        mxz = fmaxf(mxz, valid ? v.z : -INFINITY);
        mxw = fmaxf(mxw, valid ? v.w : -INFINITY);
        ++it;
    }

    if (ok) {
        float inv = 1.0f / (float)max(dg, 1);
        float m1a[4], mna[4], mxa[4], sda[4];
        m1a[0] = s1x * inv; m1a[1] = s1y * inv; m1a[2] = s1z * inv; m1a[3] = s1w * inv;
        sda[0] = sqrtf(fmaxf(s2x * inv - m1a[0] * m1a[0], 0.f) + EPS);
        sda[1] = sqrtf(fmaxf(s2y * inv - m1a[1] * m1a[1], 0.f) + EPS);
        sda[2] = sqrtf(fmaxf(s2z * inv - m1a[2] * m1a[2], 0.f) + EPS);
        sda[3] = sqrtf(fmaxf(s2w * inv - m1a[3] * m1a[3], 0.f) + EPS);
        mna[0] = mnx; mna[1] = mny; mna[2] = mnz; mna[3] = mnw;
        mxa[0] = mxx; mxa[1] = mxy; mxa[2] = mxz; mxa[3] = mxw;
        float4 aiv = ((const float4*)ai)[(size_t)r * 64 + coloff];
        float aia[4] = {aiv.x, aiv.y, aiv.z, aiv.w};
        int f0 = coloff * 4;
#pragma unroll
        for (int k = 0; k < 4; ++k) {
            int f = f0 + k;
            if (f < TD) {
                float base;
                if (dg > 0) {
                    base = aia[k] + preB[f];
                } else {
                    base = 0.f;
                    m1a[k] = 0.f; mna[k] = 0.f; mxa[k] = 0.f;
                }
                int t = f / 50, gg = f - t * 50;
                __half* col = aggT + (size_t)(t * 200 + gg) * NNP + r;
                col[0]                 = __float2half(m1a[k] + base);
                col[(size_t)50 * NNP]  = __float2half(mna[k] + base);
                col[(size_t)100 * NNP] = __float2half(mxa[k] + base);
                col[(size_t)150 * NNP] = __float2half(sda[k]);
            }
        }
    }
}

// post-NN: 256 threads = 2 wave-pairs; threads [0,128) j=0..79 + x-part,
// threads [128,256) j=80..199 -> partials via padded LDS. readfirstlane on
// the half index keeps weight loads scalar (wave-uniform).
__global__ __launch_bounds__(256) void k_post(
    const float* __restrict__ hT, const __half* __restrict__ aggT,
    const int* __restrict__ offs,
    const float* __restrict__ wT,    // [T][200][32]
    const float* __restrict__ wxT,   // [T][50][16]
    const float* __restrict__ postB, // [50]
    const float* __restrict__ avg_accum, float* __restrict__ yT) {
    __shared__ float dp[128][33];
    int t = blockIdx.x / NGRP2;
    int grp = blockIdx.x - t * NGRP2;
    int tid = threadIdx.x;
    int hf = tid >> 7, ln = tid & 127;
    int hfu = __builtin_amdgcn_readfirstlane(hf);
    int n = grp * 128 + ln;

    float acc[30];
#pragma unroll
    for (int i = 0; i < 30; ++i) acc[i] = 0.f;
    const __half* aggcol = aggT + (size_t)(t * 200) * NNP + n;
    const float4* wv = (const float4*)(wT + t * 200 * 32);
    int j0 = hfu ? 80 : 0;
    int j1 = hfu ? 200 : 80;
#pragma unroll 4
    for (int j = j0; j < j1; ++j) {
        float a = __half2float(aggcol[(size_t)j * NNP]);
        float4 w0 = wv[j * 8 + 0], w1 = wv[j * 8 + 1], w2 = wv[j * 8 + 2],
               w3 = wv[j * 8 + 3], w4 = wv[j * 8 + 4], w5 = wv[j * 8 + 5],
               w6 = wv[j * 8 + 6], w7 = wv[j * 8 + 7];
        acc[0] = fmaf(a, w0.x, acc[0]);   acc[1] = fmaf(a, w0.y, acc[1]);
        acc[2] = fmaf(a, w0.z, acc[2]);   acc[3] = fmaf(a, w0.w, acc[3]);
        acc[4] = fmaf(a, w1.x, acc[4]);   acc[5] = fmaf(a, w1.y, acc[5]);
        acc[6] = fmaf(a, w1.z, acc[6]);   acc[7] = fmaf(a, w1.w, acc[7]);
        acc[8] = fmaf(a, w2.x, acc[8]);   acc[9] = fmaf(a, w2.y, acc[9]);
        acc[10] = fmaf(a, w2.z, acc[10]); acc[11] = fmaf(a, w2.w, acc[11]);
        acc[12] = fmaf(a, w3.x, acc[12]); acc[13] = fmaf(a, w3.y, acc[13]);
        acc[14] = fmaf(a, w3.z, acc[14]); acc[15] = fmaf(a, w3.w, acc[15]);
        acc[16] = fmaf(a, w4.x, acc[16]); acc[17] = fmaf(a, w4.y, acc[17]);
        acc[18] = fmaf(a, w4.z, acc[18]); acc[19] = fmaf(a, w4.w, acc[19]);
        acc[20] = fmaf(a, w5.x, acc[20]); acc[21] = fmaf(a, w5.y, acc[21]);
        acc[22] = fmaf(a, w5.z, acc[22]); acc[23] = fmaf(a, w5.w, acc[23]);
        acc[24] = fmaf(a, w6.x, acc[24]); acc[25] = fmaf(a, w6.y, acc[25]);
        acc[26] = fmaf(a, w6.z, acc[26]); acc[27] = fmaf(a, w6.w, acc[27]);
        acc[28] = fmaf(a, w7.x, acc[28]); acc[29] = fmaf(a, w7.y, acc[29]);
    }
    float xacc[10];
#pragma unroll
    for (int i = 0; i < 10; ++i) xacc[i] = 0.f;
    if (!hfu) {
        const float4* wxv = (const float4*)(wxT + t * 50 * 16);
#pragma unroll 2
        for (int j = 0; j < 50; ++j) {
            float a = hT[(size_t)j * NNP + n];
            float4 x0 = wxv[j * 4 + 0], x1 = wxv[j * 4 + 1], x2 = wxv[j * 4 + 2];
            xacc[0] = fmaf(a, x0.x, xacc[0]); xacc[1] = fmaf(a, x0.y, xacc[1]);
            xacc[2] = fmaf(a, x0.z, xacc[2]); xacc[3] = fmaf(a, x0.w, xacc[3]);
            xacc[4] = fmaf(a, x1.x, xacc[4]); xacc[5] = fmaf(a, x1.y, xacc[5]);
            xacc[6] = fmaf(a, x1.z, xacc[6]); xacc[7] = fmaf(a, x1.w, xacc[7]);
            xacc[8] = fmaf(a, x2.x, xacc[8]); xacc[9] = fmaf(a, x2.y, xacc[9]);
        }
    } else {
#pragma unroll
        for (int g = 0; g < 30; ++g) dp[ln][g] = acc[g];
    }
    __syncthreads();
    if (!hf && n < NN) {
        int dgn = offs[n + 1] - offs[n];
        float cnt = (float)max(dgn, 1);
        float sc = logf(cnt + 1.0f) / (avg_accum[0] * (1.0f / NN));
        float isc = 1.0f / sc;
#pragma unroll
        for (int g = 0; g < 10; ++g) {
            float a0 = acc[g] + dp[ln][g];
            float a1 = acc[10 + g] + dp[ln][10 + g];
            float a2 = acc[20 + g] + dp[ln][20 + g];
            yT[(size_t)(t * FOUT + g) * NNP + n] =
                postB[t * FOUT + g] + xacc[g] + a0 + sc * a1 + isc * a2;
        }
    }
}

// 50x50 linear (pure), LDS-staged weights. 79 blocks x 256 threads.
__global__ __launch_bounds__(256) void k_lin(
    const float* __restrict__ yT, const float* __restrict__ linW,
    const float* __restrict__ linB, float* __restrict__ hrawT) {
    __shared__ float wl[2500];
    __shared__ float bl[50];
    int tid = threadIdx.x;
    int n = blockIdx.x * 256 + tid;
    for (int i = tid; i < 2500; i += 256) wl[i] = linW[i];
    if (tid < 50) bl[tid] = linB[tid];
    __syncthreads();
    float y[50];
#pragma unroll
    for (int q = 0; q < 50; ++q) y[q] = yT[(size_t)q * NNP + n];
    for (int c = 0; c < 50; ++c) {
        float a = bl[c];
        const float* w = wl + c * 50;
#pragma unroll
        for (int q = 0; q < 50; ++q) a = fmaf(w[q], y[q], a);
        hrawT[(size_t)c * NNP + n] = a;
    }
}

// BN stats: one block per channel, coalesced row reduce, direct write.
__global__ __launch_bounds__(256) void k_bnstats(const float* __restrict__ hrawT,
                                                 float* __restrict__ bn) {
    int c = blockIdx.x;
    int tid = threadIdx.x;
    const float* row = hrawT + (size_t)c * NNP;
    float s = 0.f, sq = 0.f;
    for (int n = tid; n < NN; n += 256) {
        float v = row[n];
        s += v; sq = fmaf(v, v, sq);
    }
    for (int o = 32; o > 0; o >>= 1) {
        s += __shfl_down(s, o);
        sq += __shfl_down(sq, o);
    }
    __shared__ float ws[4], wq[4];
    int lane = tid & 63, w = tid >> 6;
    if (lane == 0) { ws[w] = s; wq[w] = sq; }
    __syncthreads();
    if (tid == 0) {
        bn[c] = ws[0] + ws[1] + ws[2] + ws[3];
        bn[50 + c] = wq[0] + wq[1] + wq[2] + wq[3];
    }
}

__global__ void k_bnapply(const float* __restrict__ hrawT, const float* __restrict__ bn,
                          const float* __restrict__ gamma, const float* __restrict__ beta,
                          float* __restrict__ hT) {
    int idx = blockIdx.x * 256 + threadIdx.x;
    if (idx < D * NNP) {
        int c = idx / NNP, n = idx % NNP;
        float mean = bn[c] * (1.0f / NN);
        float var = bn[50 + c] * (1.0f / NN) - mean * mean;
        float v = gamma[c] * (hrawT[idx] - mean) * rsqrtf(var + EPS) + beta[c];
        hT[idx] = (n < NN) ? fmaxf(v, 0.f) : 0.f;
    }
}

__global__ void k_mlp(const float* __restrict__ hT, const int* __restrict__ perm,
                      const float* __restrict__ W1, const float* __restrict__ b1,
                      const float* __restrict__ W2, const float* __restrict__ b2,
                      float* __restrict__ out) {
    int n = blockIdx.x * 256 + threadIdx.x;
    if (n >= NN) return;
    float hv[50];
#pragma unroll
    for (int f = 0; f < 50; ++f) hv[f] = hT[(size_t)f * NNP + n];
    float s = b2[0];
    for (int o = 0; o < 25; ++o) {
        float a = b1[o];
        const float* w = W1 + o * 50;
#pragma unroll
        for (int f = 0; f < 50; ++f) a += w[f] * hv[f];
        s += W2[o] * fmaxf(a, 0.f);
    }
    out[perm[n]] = 1.0f / (1.0f + expf(-s));
}

// ------------------------------------------------------------------ launch
extern "C" void kernel_launch(void* const* d_in, const int* in_sizes, int n_in,
                              void* d_out, int out_size, void* d_ws, size_t ws_size,
                              hipStream_t stream) {
    const int* x = (const int*)d_in[0];
    const int* ei = (const int*)d_in[1];
    const int* src = ei;
    const int* dst = ei + NE;
    const float* emb   = (const float*)d_in[4];
    const float* preW  = (const float*)d_in[5];
    const float* preB  = (const float*)d_in[6];
    const float* postW = (const float*)d_in[7];
    const float* postB = (const float*)d_in[8];
    const float* linW  = (const float*)d_in[9];
    const float* linB  = (const float*)d_in[10];
    const float* gamma = (const float*)d_in[11];
    const float* beta  = (const float*)d_in[12];
    const float* W1 = (const float*)d_in[13];
    const float* b1 = (const float*)d_in[14];
    const float* W2 = (const float*)d_in[15];
    const float* b2 = (const float*)d_in[16];
    float* outp = (float*)d_out;

    char* wsp = (char*)d_ws;
    size_t off = 0;
    auto alloc = [&](size_t bytes) {
        void* p = wsp + off;
        off = (off + bytes + 1023) & ~(size_t)1023;
        return p;
    };
    int* deg     = (int*)alloc(NN * 4);
    int* cursor  = (int*)alloc(NN * 4);
    int* offs    = (int*)alloc((NN + 1) * 4);
    int* csr     = (int*)alloc(NE * 4);
    int* perm    = (int*)alloc(NN * 4);
    int* invp    = (int*)alloc(NN * 4);
    int* deg_r   = (int*)alloc(NN * 4);
    int* hist    = (int*)alloc(256 * 4);
    int* binbase = (int*)alloc(256 * 4);
    int* cursorb = (int*)alloc(256 * 4);
    float* bn    = (float*)alloc(512);     // [0:100) BN stats, [100] avg_log
    float* hT    = (float*)alloc((size_t)D * NNP * 4);
    float* hrawT = (float*)alloc((size_t)D * NNP * 4);
    float* yT    = (float*)alloc((size_t)D * NNP * 4);
    float* ai    = (float*)alloc((size_t)NN * ASTR * 4);
    float* aj    = (float*)alloc((size_t)NN * ASTR * 4);
    float* wT    = (float*)alloc((size_t)4 * TOWERS * 200 * 32 * 4);
    float* wxT   = (float*)alloc((size_t)4 * TOWERS * 50 * 16 * 4);
    __half* aggT = (__half*)alloc((size_t)1000 * NNP * 2);  // fp16 stats+base
    (void)ws_size; (void)in_sizes; (void)n_in; (void)out_size;

    hipMemsetAsync(deg, 0, NN * 4, stream);
    hipMemsetAsync(cursor, 0, NN * 4, stream);
    hipMemsetAsync(hist, 0, 256 * 4, stream);
    hipMemsetAsync(cursorb, 0, 256 * 4, stream);
    hipMemsetAsync(bn, 0, 512, stream);

    k_deg<<<(NE + 255) / 256, 256, 0, stream>>>(dst, deg);
    k_hist<<<(NN + 255) / 256, 256, 0, stream>>>(deg, hist);
    k_binscan<<<1, 256, 0, stream>>>(hist, binbase);
    k_scatter<<<(NN + 255) / 256, 256, 0, stream>>>(deg, binbase, cursorb, perm, invp, deg_r);
    k_scan<<<1, 1024, 0, stream>>>(deg_r, offs);
    k_csr<<<(NE + 255) / 256, 256, 0, stream>>>(src, dst, offs, invp, cursor, csr);
    k_avglog<<<(NN + 255) / 256, 256, 0, stream>>>(deg, bn + 100);
    k_emb<<<(D * NNP + 255) / 256, 256, 0, stream>>>(x, emb, perm, hT);
    k_wt<<<(4 * TOWERS * 200 * 32 + 4 * TOWERS * 50 * 16 + 255) / 256, 256, 0, stream>>>(postW, wT, wxT);

    int aggblocks = 313 * 8;
    for (int l = 0; l < 4; ++l) {
        k_pre<<<NN / PRE_NT, 512, 0, stream>>>(hT, preW + l * TD * 100, ai, aj);
        k_agg<<<aggblocks, 512, 0, stream>>>(aj, offs, csr, ai, preB + l * TD, aggT);
        k_post<<<NGRP2 * TOWERS, 256, 0, stream>>>(hT, aggT, offs,
                                                   wT + l * TOWERS * 200 * 32,
                                                   wxT + l * TOWERS * 50 * 16,
                                                   postB + l * 50, bn + 100, yT);
        k_lin<<<NNP / 256, 256, 0, stream>>>(yT, linW + l * 2500, linB + l * 50, hrawT);
        k_bnstats<<<50, 256, 0, stream>>>(hrawT, bn);
        k_bnapply<<<(D * NNP + 255) / 256, 256, 0, stream>>>(hrawT, bn, gamma + l * 50,
                                                             beta + l * 50, hT);
    }
    k_mlp<<<(NN + 255) / 256, 256, 0, stream>>>(hT, perm, W1, b1, W2, b2, outp);
}

// Round 13
// 804.635 us; speedup vs baseline: 1.8941x; 1.0638x over previous
//
#include <hip/hip_runtime.h>
#include <hip/hip_fp16.h>
#include <math.h>

#define NN 20000
#define NNP 20224   // padded to 158*128 (= 79*256)
#define NGRP2 158   // NNP/128
#define NE 320000
#define D 50
#define TOWERS 5
#define TD 250      // TOWERS*D
#define ASTR 256    // padded row stride for ai/aj
#define FOUT 10
#define EPS 1e-5f

// ------------------------------------------------------------------ setup
__global__ void k_deg(const int* __restrict__ dst, int* __restrict__ deg) {
    int e = blockIdx.x * 256 + threadIdx.x;
    if (e < NE) atomicAdd(&deg[dst[e]], 1);
}

// LDS-privatized histogram: per-block LDS bins, then <=256 global adds per
// block (the naive version serialized ~2000 same-address global atomics on
// the Poisson mode bins -> 53 us of pure stall).
__global__ __launch_bounds__(256) void k_hist(const int* __restrict__ deg,
                                              int* __restrict__ hist) {
    __shared__ int lh[256];
    int tid = threadIdx.x;
    lh[tid] = 0;
    __syncthreads();
    int n = blockIdx.x * 256 + tid;
    if (n < NN) atomicAdd(&lh[min(deg[n], 255)], 1);
    __syncthreads();
    if (lh[tid] > 0) atomicAdd(&hist[tid], lh[tid]);
}

__global__ void k_binscan(const int* __restrict__ hist, int* __restrict__ binbase) {
    __shared__ int b[256];
    int tid = threadIdx.x;
    b[tid] = hist[tid];
    __syncthreads();
    for (int off = 1; off < 256; off <<= 1) {
        int t = (tid >= off) ? b[tid - off] : 0;
        __syncthreads();
        b[tid] += t;
        __syncthreads();
    }
    binbase[tid] = b[tid] - hist[tid];   // exclusive
}

// LDS-histogram scatter: block counts bins locally, reserves one global
// range per (bin, block) -> 256 distributed atomics/block.
__global__ __launch_bounds__(256) void k_scatter(
    const int* __restrict__ deg, const int* __restrict__ binbase,
    int* __restrict__ cursorb, int* __restrict__ perm,
    int* __restrict__ invp, int* __restrict__ deg_r) {
    __shared__ int lh[256];
    __shared__ int lbase[256];
    int tid = threadIdx.x;
    lh[tid] = 0;
    __syncthreads();
    int n = blockIdx.x * 256 + tid;
    int d = 0, slot = 0;
    bool ok = n < NN;
    if (ok) {
        d = min(deg[n], 255);
        slot = atomicAdd(&lh[d], 1);
    }
    __syncthreads();
    if (lh[tid] > 0) lbase[tid] = atomicAdd(&cursorb[tid], lh[tid]);
    __syncthreads();
    if (ok) {
        int r = binbase[d] + lbase[d] + slot;
        perm[r] = n;
        invp[n] = r;
        deg_r[r] = deg[n];
    }
}

__global__ void k_scan(const int* __restrict__ deg, int* __restrict__ offs) {
    __shared__ int buf[1024];
    __shared__ int carry;
    int tid = threadIdx.x;
    if (tid == 0) carry = 0;
    __syncthreads();
    for (int base = 0; base < NN; base += 1024) {
        int i = base + tid;
        int v = (i < NN) ? deg[i] : 0;
        buf[tid] = v;
        __syncthreads();
        for (int off = 1; off < 1024; off <<= 1) {
            int t = (tid >= off) ? buf[tid - off] : 0;
            __syncthreads();
            buf[tid] += t;
            __syncthreads();
        }
        int excl = carry + buf[tid] - v;
        if (i < NN) offs[i] = excl;
        __syncthreads();
        if (tid == 0) carry += buf[1023];
        __syncthreads();
    }
    if (tid == 0) offs[NN] = carry;        // == NE
}

__global__ void k_csr(const int* __restrict__ src, const int* __restrict__ dst,
                      const int* __restrict__ offs, const int* __restrict__ invp,
                      int* __restrict__ cursor, int* __restrict__ csr_src) {
    int e = blockIdx.x * 256 + threadIdx.x;
    if (e < NE) {
        int rd = invp[dst[e]];
        int slot = atomicAdd(&cursor[rd], 1);
        csr_src[offs[rd] + slot] = invp[src[e]];
    }
}

__global__ void k_avglog(const int* __restrict__ deg, float* __restrict__ accum) {
    int n = blockIdx.x * 256 + threadIdx.x;
    float v = (n < NN) ? logf((float)deg[n] + 1.0f) : 0.0f;
    for (int o = 32; o > 0; o >>= 1) v += __shfl_down(v, o);
    __shared__ float wsum[4];
    int lane = threadIdx.x & 63, w = threadIdx.x >> 6;
    if (lane == 0) wsum[w] = v;
    __syncthreads();
    if (threadIdx.x == 0) atomicAdd(accum, wsum[0] + wsum[1] + wsum[2] + wsum[3]);
}

// embedding -> hT (feature-major, RANK space), zero pad columns
__global__ void k_emb(const int* __restrict__ x, const float* __restrict__ emb,
                      const int* __restrict__ perm, float* __restrict__ hT) {
    int idx = blockIdx.x * 256 + threadIdx.x;
    if (idx < D * NNP) {
        int c = idx / NNP, r = idx % NNP;
        hT[idx] = (r < NN) ? emb[x[perm[r]] * D + c] : 0.f;
    }
}

// transpose postW (all layers) into wT[l][t][200][32] (c = p*10+g, pad 30,31)
// and wxT[l][t][50][16] (c = g, pad 10..15) for scalar-broadcast GEMV.
__global__ void k_wt(const float* __restrict__ postW, float* __restrict__ wT,
                     float* __restrict__ wxT) {
    int idx = blockIdx.x * 256 + threadIdx.x;
    const int WTN = 4 * TOWERS * 200 * 32;
    if (idx < WTN) {
        int l = idx / (TOWERS * 200 * 32);
        int r = idx % (TOWERS * 200 * 32);
        int t = r / (200 * 32); r %= 200 * 32;
        int j = r / 32, c = r % 32;
        float v = 0.f;
        if (c < 30) {
            int p = c / 10, g = c % 10;
            v = postW[l * 32500 + (t * FOUT + g) * 650 + 50 + p * 200 + j];
        }
        wT[idx] = v;
    } else if (idx < WTN + 4 * TOWERS * 50 * 16) {
        int k = idx - WTN;
        int l = k / (TOWERS * 50 * 16);
        int r = k % (TOWERS * 50 * 16);
        int t = r / (50 * 16); r %= 50 * 16;
        int j = r / 16, c = r % 16;
        float v = 0.f;
        if (c < 10) v = postW[l * 32500 + (t * FOUT + c) * 650 + j];
        wxT[k] = v;
    }
}

// ------------------------------------------------------------- per layer
// pre-NN: 512 threads, thread o<250 -> ai row o, 250<=o<500 -> aj row o-250
// (50 W floats in registers each). x tile (32 nodes) in LDS as float4.
#define PRE_NT 32
__global__ __launch_bounds__(512) void k_pre(const float* __restrict__ hT,
                                             const float* __restrict__ preW, // [TD][2D]
                                             float* __restrict__ ai,
                                             float* __restrict__ aj) {
    __shared__ float xl[PRE_NT * 52];
    int n0 = blockIdx.x * PRE_NT;
    int tid = threadIdx.x;
    for (int k = tid; k < PRE_NT * 52; k += 512) {
        int nl = k & 31, f = k >> 5;
        xl[nl * 52 + f] = (f < 50) ? hT[(size_t)f * NNP + n0 + nl] : 0.f;
    }
    __syncthreads();
    int o = tid;
    if (o < 500) {
        int isj = (o >= 250) ? 1 : 0;
        int oo = o - isj * 250;
        const float* w0 = preW + oo * 100 + isj * 50;
        float w[52];
#pragma unroll
        for (int f = 0; f < 50; ++f) w[f] = w0[f];
        w[50] = 0.f; w[51] = 0.f;
        float* dstp = isj ? aj : ai;
        for (int nl = 0; nl < PRE_NT; ++nl) {
            const float4* xv = (const float4*)&xl[nl * 52];
            float a = 0.f;
#pragma unroll
            for (int j = 0; j < 13; ++j) {
                float4 x4 = xv[j];
                a = fmaf(x4.x, w[4 * j], a);
                a = fmaf(x4.y, w[4 * j + 1], a);
                a = fmaf(x4.z, w[4 * j + 2], a);
                a = fmaf(x4.w, w[4 * j + 3], a);
            }
            dstp[(size_t)(n0 + nl) * ASTR + oo] = a;
        }
    } else {                       // threads 500..511: zero pad cols 250..255
        int p = o - 500;
        int oo = 250 + (p % 6);
        float* dstp = (p < 6) ? ai : aj;
        for (int nl = 0; nl < PRE_NT; ++nl)
            dstp[(size_t)(n0 + nl) * ASTR + oo] = 0.f;
    }
}

#define ACCV(v) do { \
    s1x += v.x; s1y += v.y; s1z += v.z; s1w += v.w; \
    s2x = fmaf(v.x, v.x, s2x); s2y = fmaf(v.y, v.y, s2y); \
    s2z = fmaf(v.z, v.z, s2z); s2w = fmaf(v.w, v.w, s2w); \
    mnx = fminf(mnx, v.x); mny = fminf(mny, v.y); \
    mnz = fminf(mnz, v.z); mnw = fminf(mnw, v.w); \
    mxx = fmaxf(mxx, v.x); mxy = fmaxf(mxy, v.y); \
    mxz = fmaxf(mxz, v.z); mxw = fmaxf(mxw, v.w); \
} while (0)

// Edge aggregation, RANK space (degree-sorted). Grid = 313 nodeblocks x 8
// chunks; chunk = low 3 bits (XCD-pinned); nodeblocks REVERSED so the
// high-degree blocks launch first (tail packing). fp16 output.
__global__ __launch_bounds__(512) void k_agg(
    const float* __restrict__ aj, const int* __restrict__ offs,
    const int* __restrict__ csr_src, const float* __restrict__ ai,
    const float* __restrict__ preB, __half* __restrict__ aggT) {
    int chunk = blockIdx.x & 7;
    int nb = (gridDim.x >> 3) - 1 - (blockIdx.x >> 3);   // reversed
    int tid = threadIdx.x;
    int wave = tid >> 6, lane = tid & 63;
    int g = lane >> 2, q = lane & 3;
    int r = nb * 64 + (wave >> 1) * 16 + g;
    int coloff = chunk * 8 + (wave & 1) * 4 + q;
    bool ok = r < NN;
    int e0 = 0, dg = 0;
    if (ok) { e0 = offs[r]; dg = offs[r + 1] - e0; }
    int mdeg = dg;
#pragma unroll
    for (int o = 4; o < 64; o <<= 1) mdeg = min(mdeg, __shfl_xor(mdeg, o));

    const float4* ajv = (const float4*)aj;
    float s1x = 0.f, s1y = 0.f, s1z = 0.f, s1w = 0.f;
    float s2x = 0.f, s2y = 0.f, s2z = 0.f, s2w = 0.f;
    float mnx = INFINITY, mny = INFINITY, mnz = INFINITY, mnw = INFINITY;
    float mxx = -INFINITY, mxy = -INFINITY, mxz = -INFINITY, mxw = -INFINITY;

    int it = 0;
    for (; it + 4 <= mdeg; it += 4) {         // uniform, 4 loads in flight
        int s0 = csr_src[e0 + it];
        int s1 = csr_src[e0 + it + 1];
        int s2 = csr_src[e0 + it + 2];
        int s3 = csr_src[e0 + it + 3];
        float4 v0 = ajv[((unsigned)s0 << 6) + coloff];
        float4 v1 = ajv[((unsigned)s1 << 6) + coloff];
        float4 v2 = ajv[((unsigned)s2 << 6) + coloff];
        float4 v3 = ajv[((unsigned)s3 << 6) + coloff];
        ACCV(v0); ACCV(v1); ACCV(v2); ACCV(v3);
    }
    for (; it < mdeg; ++it) {
        int s = csr_src[e0 + it];
        float4 v = ajv[((unsigned)s << 6) + coloff];
        ACCV(v);
    }
    while (__any(it < dg)) {                  // tiny tail (bin boundaries)
        bool valid = it < dg;
        int s = csr_src[valid ? e0 + it : e0];
        float4 v = ajv[((unsigned)s << 6) + coloff];
        float zx = valid ? v.x : 0.f, zy = valid ? v.y : 0.f;
        float zz = valid ? v.z : 0.f, zw = valid ? v.w : 0.f;
        s1x += zx; s1y += zy; s1z += zz; s1w += zw;
        s2x = fmaf(zx, zx, s2x); s2y = fmaf(zy, zy, s2y);
        s2z = fmaf(zz, zz, s2z); s2w = fmaf(zw, zw, s2w);
        mnx = fminf(mnx, valid ? v.x : INFINITY);
        mny = fminf(mny, valid ? v.y : INFINITY);
        mnz = fminf(mnz, valid ? v.z : INFINITY);
        mnw = fminf(mnw, valid ? v.w : INFINITY);
        mxx = fmaxf(mxx, valid ? v.x : -INFINITY);
        mxy = fmaxf(mxy, valid ? v.y : -INFINITY);
        mxz = fmaxf(mxz, valid ? v.z : -INFINITY);
        mxw = fmaxf(mxw, valid ? v.w : -INFINITY);
        ++it;
    }

    if (ok) {
        float inv = 1.0f / (float)max(dg, 1);
        float m1a[4], mna[4], mxa[4], sda[4];
        m1a[0] = s1x * inv; m1a[1] = s1y * inv; m1a[2] = s1z * inv; m1a[3] = s1w * inv;
        sda[0] = sqrtf(fmaxf(s2x * inv - m1a[0] * m1a[0], 0.f) + EPS);
        sda[1] = sqrtf(fmaxf(s2y * inv - m1a[1] * m1a[1], 0.f) + EPS);
        sda[2] = sqrtf(fmaxf(s2z * inv - m1a[2] * m1a[2], 0.f) + EPS);
        sda[3] = sqrtf(fmaxf(s2w * inv - m1a[3] * m1a[3], 0.f) + EPS);
        mna[0] = mnx; mna[1] = mny; mna[2] = mnz; mna[3] = mnw;
        mxa[0] = mxx; mxa[1] = mxy; mxa[2] = mxz; mxa[3] = mxw;
        float4 aiv = ((const float4*)ai)[(size_t)r * 64 + coloff];
        float aia[4] = {aiv.x, aiv.y, aiv.z, aiv.w};
        int f0 = coloff * 4;
#pragma unroll
        for (int k = 0; k < 4; ++k) {
            int f = f0 + k;
            if (f < TD) {
                float base;
                if (dg > 0) {
                    base = aia[k] + preB[f];
                } else {
                    base = 0.f;
                    m1a[k] = 0.f; mna[k] = 0.f; mxa[k] = 0.f;
                }
                int t = f / 50, gg = f - t * 50;
                __half* col = aggT + (size_t)(t * 200 + gg) * NNP + r;
                col[0]                 = __float2half(m1a[k] + base);
                col[(size_t)50 * NNP]  = __float2half(mna[k] + base);
                col[(size_t)100 * NNP] = __float2half(mxa[k] + base);
                col[(size_t)150 * NNP] = __float2half(sda[k]);
            }
        }
    }
}

// post-NN: 256 threads = 2 wave-pairs; threads [0,128) j=0..79 + x-part,
// threads [128,256) j=80..199 -> partials via padded LDS. readfirstlane on
// the half index keeps weight loads scalar (wave-uniform).
__global__ __launch_bounds__(256) void k_post(
    const float* __restrict__ hT, const __half* __restrict__ aggT,
    const int* __restrict__ offs,
    const float* __restrict__ wT,    // [T][200][32]
    const float* __restrict__ wxT,   // [T][50][16]
    const float* __restrict__ postB, // [50]
    const float* __restrict__ avg_accum, float* __restrict__ yT) {
    __shared__ float dp[128][33];
    int t = blockIdx.x / NGRP2;
    int grp = blockIdx.x - t * NGRP2;
    int tid = threadIdx.x;
    int hf = tid >> 7, ln = tid & 127;
    int hfu = __builtin_amdgcn_readfirstlane(hf);
    int n = grp * 128 + ln;

    float acc[30];
#pragma unroll
    for (int i = 0; i < 30; ++i) acc[i] = 0.f;
    const __half* aggcol = aggT + (size_t)(t * 200) * NNP + n;
    const float4* wv = (const float4*)(wT + t * 200 * 32);
    int j0 = hfu ? 80 : 0;
    int j1 = hfu ? 200 : 80;
#pragma unroll 4
    for (int j = j0; j < j1; ++j) {
        float a = __half2float(aggcol[(size_t)j * NNP]);
        float4 w0 = wv[j * 8 + 0], w1 = wv[j * 8 + 1], w2 = wv[j * 8 + 2],
               w3 = wv[j * 8 + 3], w4 = wv[j * 8 + 4], w5 = wv[j * 8 + 5],
               w6 = wv[j * 8 + 6], w7 = wv[j * 8 + 7];
        acc[0] = fmaf(a, w0.x, acc[0]);   acc[1] = fmaf(a, w0.y, acc[1]);
        acc[2] = fmaf(a, w0.z, acc[2]);   acc[3] = fmaf(a, w0.w, acc[3]);
        acc[4] = fmaf(a, w1.x, acc[4]);   acc[5] = fmaf(a, w1.y, acc[5]);
        acc[6] = fmaf(a, w1.z, acc[6]);   acc[7] = fmaf(a, w1.w, acc[7]);
        acc[8] = fmaf(a, w2.x, acc[8]);   acc[9] = fmaf(a, w2.y, acc[9]);
        acc[10] = fmaf(a, w2.z, acc[10]); acc[11] = fmaf(a, w2.w, acc[11]);
        acc[12] = fmaf(a, w3.x, acc[12]); acc[13] = fmaf(a, w3.y, acc[13]);
        acc[14] = fmaf(a, w3.z, acc[14]); acc[15] = fmaf(a, w3.w, acc[15]);
        acc[16] = fmaf(a, w4.x, acc[16]); acc[17] = fmaf(a, w4.y, acc[17]);
        acc[18] = fmaf(a, w4.z, acc[18]); acc[19] = fmaf(a, w4.w, acc[19]);
        acc[20] = fmaf(a, w5.x, acc[20]); acc[21] = fmaf(a, w5.y, acc[21]);
        acc[22] = fmaf(a, w5.z, acc[22]); acc[23] = fmaf(a, w5.w, acc[23]);
        acc[24] = fmaf(a, w6.x, acc[24]); acc[25] = fmaf(a, w6.y, acc[25]);
        acc[26] = fmaf(a, w6.z, acc[26]); acc[27] = fmaf(a, w6.w, acc[27]);
        acc[28] = fmaf(a, w7.x, acc[28]); acc[29] = fmaf(a, w7.y, acc[29]);
    }
    float xacc[10];
#pragma unroll
    for (int i = 0; i < 10; ++i) xacc[i] = 0.f;
    if (!hfu) {
        const float4* wxv = (const float4*)(wxT + t * 50 * 16);
#pragma unroll 2
        for (int j = 0; j < 50; ++j) {
            float a = hT[(size_t)j * NNP + n];
            float4 x0 = wxv[j * 4 + 0], x1 = wxv[j * 4 + 1], x2 = wxv[j * 4 + 2];
            xacc[0] = fmaf(a, x0.x, xacc[0]); xacc[1] = fmaf(a, x0.y, xacc[1]);
            xacc[2] = fmaf(a, x0.z, xacc[2]); xacc[3] = fmaf(a, x0.w, xacc[3]);
            xacc[4] = fmaf(a, x1.x, xacc[4]); xacc[5] = fmaf(a, x1.y, xacc[5]);
            xacc[6] = fmaf(a, x1.z, xacc[6]); xacc[7] = fmaf(a, x1.w, xacc[7]);
            xacc[8] = fmaf(a, x2.x, xacc[8]); xacc[9] = fmaf(a, x2.y, xacc[9]);
        }
    } else {
#pragma unroll
        for (int g = 0; g < 30; ++g) dp[ln][g] = acc[g];
    }
    __syncthreads();
    if (!hf && n < NN) {
        int dgn = offs[n + 1] - offs[n];
        float cnt = (float)max(dgn, 1);
        float sc = logf(cnt + 1.0f) / (avg_accum[0] * (1.0f / NN));
        float isc = 1.0f / sc;
#pragma unroll
        for (int g = 0; g < 10; ++g) {
            float a0 = acc[g] + dp[ln][g];
            float a1 = acc[10 + g] + dp[ln][10 + g];
            float a2 = acc[20 + g] + dp[ln][20 + g];
            yT[(size_t)(t * FOUT + g) * NNP + n] =
                postB[t * FOUT + g] + xacc[g] + a0 + sc * a1 + isc * a2;
        }
    }
}

// 50x50 linear (pure), LDS-staged weights. 79 blocks x 256 threads.
__global__ __launch_bounds__(256) void k_lin(
    const float* __restrict__ yT, const float* __restrict__ linW,
    const float* __restrict__ linB, float* __restrict__ hrawT) {
    __shared__ float wl[2500];
    __shared__ float bl[50];
    int tid = threadIdx.x;
    int n = blockIdx.x * 256 + tid;
    for (int i = tid; i < 2500; i += 256) wl[i] = linW[i];
    if (tid < 50) bl[tid] = linB[tid];
    __syncthreads();
    float y[50];
#pragma unroll
    for (int q = 0; q < 50; ++q) y[q] = yT[(size_t)q * NNP + n];
    for (int c = 0; c < 50; ++c) {
        float a = bl[c];
        const float* w = wl + c * 50;
#pragma unroll
        for (int q = 0; q < 50; ++q) a = fmaf(w[q], y[q], a);
        hrawT[(size_t)c * NNP + n] = a;
    }
}

// BN stats: one block per channel, coalesced row reduce, direct write.
__global__ __launch_bounds__(256) void k_bnstats(const float* __restrict__ hrawT,
                                                 float* __restrict__ bn) {
    int c = blockIdx.x;
    int tid = threadIdx.x;
    const float* row = hrawT + (size_t)c * NNP;
    float s = 0.f, sq = 0.f;
    for (int n = tid; n < NN; n += 256) {
        float v = row[n];
        s += v; sq = fmaf(v, v, sq);
    }
    for (int o = 32; o > 0; o >>= 1) {
        s += __shfl_down(s, o);
        sq += __shfl_down(sq, o);
    }
    __shared__ float ws[4], wq[4];
    int lane = tid & 63, w = tid >> 6;
    if (lane == 0) { ws[w] = s; wq[w] = sq; }
    __syncthreads();
    if (tid == 0) {
        bn[c] = ws[0] + ws[1] + ws[2] + ws[3];
        bn[50 + c] = wq[0] + wq[1] + wq[2] + wq[3];
    }
}

__global__ void k_bnapply(const float* __restrict__ hrawT, const float* __restrict__ bn,
                          const float* __restrict__ gamma, const float* __restrict__ beta,
                          float* __restrict__ hT) {
    int idx = blockIdx.x * 256 + threadIdx.x;
    if (idx < D * NNP) {
        int c = idx / NNP, n = idx % NNP;
        float mean = bn[c] * (1.0f / NN);
        float var = bn[50 + c] * (1.0f / NN) - mean * mean;
        float v = gamma[c] * (hrawT[idx] - mean) * rsqrtf(var + EPS) + beta[c];
        hT[idx] = (n < NN) ? fmaxf(v, 0.f) : 0.f;
    }
}

__global__ void k_mlp(const float* __restrict__ hT, const int* __restrict__ perm,
                      const float* __restrict__ W1, const float* __restrict__ b1,
                      const float* __restrict__ W2, const float* __restrict__ b2,
                      float* __restrict__ out) {
    int n = blockIdx.x * 256 + threadIdx.x;
    if (n >= NN) return;
    float hv[50];
#pragma unroll
    for (int f = 0; f < 50; ++f) hv[f] = hT[(size_t)f * NNP + n];
    float s = b2[0];
    for (int o = 0; o < 25; ++o) {
        float a = b1[o];
        const float* w = W1 + o * 50;
#pragma unroll
        for (int f = 0; f < 50; ++f) a += w[f] * hv[f];
        s += W2[o] * fmaxf(a, 0.f);
    }
    out[perm[n]] = 1.0f / (1.0f + expf(-s));
}

// ------------------------------------------------------------------ launch
extern "C" void kernel_launch(void* const* d_in, const int* in_sizes, int n_in,
                              void* d_out, int out_size, void* d_ws, size_t ws_size,
                              hipStream_t stream) {
    const int* x = (const int*)d_in[0];
    const int* ei = (const int*)d_in[1];
    const int* src = ei;
    const int* dst = ei + NE;
    const float* emb   = (const float*)d_in[4];
    const float* preW  = (const float*)d_in[5];
    const float* preB  = (const float*)d_in[6];
    const float* postW = (const float*)d_in[7];
    const float* postB = (const float*)d_in[8];
    const float* linW  = (const float*)d_in[9];
    const float* linB  = (const float*)d_in[10];
    const float* gamma = (const float*)d_in[11];
    const float* beta  = (const float*)d_in[12];
    const float* W1 = (const float*)d_in[13];
    const float* b1 = (const float*)d_in[14];
    const float* W2 = (const float*)d_in[15];
    const float* b2 = (const float*)d_in[16];
    float* outp = (float*)d_out;

    char* wsp = (char*)d_ws;
    size_t off = 0;
    auto alloc = [&](size_t bytes) {
        void* p = wsp + off;
        off = (off + bytes + 1023) & ~(size_t)1023;
        return p;
    };
    int* deg     = (int*)alloc(NN * 4);
    int* cursor  = (int*)alloc(NN * 4);
    int* offs    = (int*)alloc((NN + 1) * 4);
    int* csr     = (int*)alloc(NE * 4);
    int* perm    = (int*)alloc(NN * 4);
    int* invp    = (int*)alloc(NN * 4);
    int* deg_r   = (int*)alloc(NN * 4);
    int* hist    = (int*)alloc(256 * 4);
    int* binbase = (int*)alloc(256 * 4);
    int* cursorb = (int*)alloc(256 * 4);
    float* bn    = (float*)alloc(512);     // [0:100) BN stats, [100] avg_log
    float* hT    = (float*)alloc((size_t)D * NNP * 4);
    float* hrawT = (float*)alloc((size_t)D * NNP * 4);
    float* yT    = (float*)alloc((size_t)D * NNP * 4);
    float* ai    = (float*)alloc((size_t)NN * ASTR * 4);
    float* aj    = (float*)alloc((size_t)NN * ASTR * 4);
    float* wT    = (float*)alloc((size_t)4 * TOWERS * 200 * 32 * 4);
    float* wxT   = (float*)alloc((size_t)4 * TOWERS * 50 * 16 * 4);
    __half* aggT = (__half*)alloc((size_t)1000 * NNP * 2);  // fp16 stats+base
    (void)ws_size; (void)in_sizes; (void)n_in; (void)out_size;

    hipMemsetAsync(deg, 0, NN * 4, stream);
    hipMemsetAsync(cursor, 0, NN * 4, stream);
    hipMemsetAsync(hist, 0, 256 * 4, stream);
    hipMemsetAsync(cursorb, 0, 256 * 4, stream);
    hipMemsetAsync(bn, 0, 512, stream);

    k_deg<<<(NE + 255) / 256, 256, 0, stream>>>(dst, deg);
    k_hist<<<(NN + 255) / 256, 256, 0, stream>>>(deg, hist);
    k_binscan<<<1, 256, 0, stream>>>(hist, binbase);
    k_scatter<<<(NN + 255) / 256, 256, 0, stream>>>(deg, binbase, cursorb, perm, invp, deg_r);
    k_scan<<<1, 1024, 0, stream>>>(deg_r, offs);
    k_csr<<<(NE + 255) / 256, 256, 0, stream>>>(src, dst, offs, invp, cursor, csr);
    k_avglog<<<(NN + 255) / 256, 256, 0, stream>>>(deg, bn + 100);
    k_emb<<<(D * NNP + 255) / 256, 256, 0, stream>>>(x, emb, perm, hT);
    k_wt<<<(4 * TOWERS * 200 * 32 + 4 * TOWERS * 50 * 16 + 255) / 256, 256, 0, stream>>>(postW, wT, wxT);

    int aggblocks = 313 * 8;
    for (int l = 0; l < 4; ++l) {
        k_pre<<<NN / PRE_NT, 512, 0, stream>>>(hT, preW + l * TD * 100, ai, aj);
        k_agg<<<aggblocks, 512, 0, stream>>>(aj, offs, csr, ai, preB + l * TD, aggT);
        k_post<<<NGRP2 * TOWERS, 256, 0, stream>>>(hT, aggT, offs,
                                                   wT + l * TOWERS * 200 * 32,
                                                   wxT + l * TOWERS * 50 * 16,
                                                   postB + l * 50, bn + 100, yT);
        k_lin<<<NNP / 256, 256, 0, stream>>>(yT, linW + l * 2500, linB + l * 50, hrawT);
        k_bnstats<<<50, 256, 0, stream>>>(hrawT, bn);
        k_bnapply<<<(D * NNP + 255) / 256, 256, 0, stream>>>(hrawT, bn, gamma + l * 50,
                                                             beta + l * 50, hT);
    }
    k_mlp<<<(NN + 255) / 256, 256, 0, stream>>>(hT, perm, W1, b1, W2, b2, outp);
}

// Round 14
// 741.360 us; speedup vs baseline: 2.0557x; 1.0853x over previous
//
#include <hip/hip_runtime.h>
#include <hip/hip_fp16.h>
#include <math.h>

#define NN 20000
#define NNP 20224   // padded to 158*128 (= 79*256)
#define NGRP2 158   // NNP/128
#define NE 320000
#define D 50
#define TOWERS 5
#define TD 250      // TOWERS*D
#define ASTR 256    // padded row stride for ai/aj
#define FOUT 10
#define EPS 1e-5f

// ------------------------------------------------------------------ setup
__global__ void k_deg(const int* __restrict__ dst, int* __restrict__ deg) {
    int e = blockIdx.x * 256 + threadIdx.x;
    if (e < NE) atomicAdd(&deg[dst[e]], 1);
}

// LDS-privatized histogram (same-address global atomics were 53 us).
__global__ __launch_bounds__(256) void k_hist(const int* __restrict__ deg,
                                              int* __restrict__ hist) {
    __shared__ int lh[256];
    int tid = threadIdx.x;
    lh[tid] = 0;
    __syncthreads();
    int n = blockIdx.x * 256 + tid;
    if (n < NN) atomicAdd(&lh[min(deg[n], 255)], 1);
    __syncthreads();
    if (lh[tid] > 0) atomicAdd(&hist[tid], lh[tid]);
}

__global__ void k_binscan(const int* __restrict__ hist, int* __restrict__ binbase) {
    __shared__ int b[256];
    int tid = threadIdx.x;
    b[tid] = hist[tid];
    __syncthreads();
    for (int off = 1; off < 256; off <<= 1) {
        int t = (tid >= off) ? b[tid - off] : 0;
        __syncthreads();
        b[tid] += t;
        __syncthreads();
    }
    binbase[tid] = b[tid] - hist[tid];   // exclusive
}

// LDS-histogram scatter: one global range reservation per (bin, block).
__global__ __launch_bounds__(256) void k_scatter(
    const int* __restrict__ deg, const int* __restrict__ binbase,
    int* __restrict__ cursorb, int* __restrict__ perm,
    int* __restrict__ invp, int* __restrict__ deg_r) {
    __shared__ int lh[256];
    __shared__ int lbase[256];
    int tid = threadIdx.x;
    lh[tid] = 0;
    __syncthreads();
    int n = blockIdx.x * 256 + tid;
    int d = 0, slot = 0;
    bool ok = n < NN;
    if (ok) {
        d = min(deg[n], 255);
        slot = atomicAdd(&lh[d], 1);
    }
    __syncthreads();
    if (lh[tid] > 0) lbase[tid] = atomicAdd(&cursorb[tid], lh[tid]);
    __syncthreads();
    if (ok) {
        int r = binbase[d] + lbase[d] + slot;
        perm[r] = n;
        invp[n] = r;
        deg_r[r] = deg[n];
    }
}

__global__ void k_scan(const int* __restrict__ deg, int* __restrict__ offs) {
    __shared__ int buf[1024];
    __shared__ int carry;
    int tid = threadIdx.x;
    if (tid == 0) carry = 0;
    __syncthreads();
    for (int base = 0; base < NN; base += 1024) {
        int i = base + tid;
        int v = (i < NN) ? deg[i] : 0;
        buf[tid] = v;
        __syncthreads();
        for (int off = 1; off < 1024; off <<= 1) {
            int t = (tid >= off) ? buf[tid - off] : 0;
            __syncthreads();
            buf[tid] += t;
            __syncthreads();
        }
        int excl = carry + buf[tid] - v;
        if (i < NN) offs[i] = excl;
        __syncthreads();
        if (tid == 0) carry += buf[1023];
        __syncthreads();
    }
    if (tid == 0) offs[NN] = carry;        // == NE
}

__global__ void k_csr(const int* __restrict__ src, const int* __restrict__ dst,
                      const int* __restrict__ offs, const int* __restrict__ invp,
                      int* __restrict__ cursor, int* __restrict__ csr_src) {
    int e = blockIdx.x * 256 + threadIdx.x;
    if (e < NE) {
        int rd = invp[dst[e]];
        int slot = atomicAdd(&cursor[rd], 1);
        csr_src[offs[rd] + slot] = invp[src[e]];
    }
}

__global__ void k_avglog(const int* __restrict__ deg, float* __restrict__ accum) {
    int n = blockIdx.x * 256 + threadIdx.x;
    float v = (n < NN) ? logf((float)deg[n] + 1.0f) : 0.0f;
    for (int o = 32; o > 0; o >>= 1) v += __shfl_down(v, o);
    __shared__ float wsum[4];
    int lane = threadIdx.x & 63, w = threadIdx.x >> 6;
    if (lane == 0) wsum[w] = v;
    __syncthreads();
    if (threadIdx.x == 0) atomicAdd(accum, wsum[0] + wsum[1] + wsum[2] + wsum[3]);
}

// embedding -> hT (feature-major, RANK space), zero pad columns
__global__ void k_emb(const int* __restrict__ x, const float* __restrict__ emb,
                      const int* __restrict__ perm, float* __restrict__ hT) {
    int idx = blockIdx.x * 256 + threadIdx.x;
    if (idx < D * NNP) {
        int c = idx / NNP, r = idx % NNP;
        hT[idx] = (r < NN) ? emb[x[perm[r]] * D + c] : 0.f;
    }
}

// transpose postW (all layers) into wT[l][t][200][32] and wxT[l][t][50][16].
__global__ void k_wt(const float* __restrict__ postW, float* __restrict__ wT,
                     float* __restrict__ wxT) {
    int idx = blockIdx.x * 256 + threadIdx.x;
    const int WTN = 4 * TOWERS * 200 * 32;
    if (idx < WTN) {
        int l = idx / (TOWERS * 200 * 32);
        int r = idx % (TOWERS * 200 * 32);
        int t = r / (200 * 32); r %= 200 * 32;
        int j = r / 32, c = r % 32;
        float v = 0.f;
        if (c < 30) {
            int p = c / 10, g = c % 10;
            v = postW[l * 32500 + (t * FOUT + g) * 650 + 50 + p * 200 + j];
        }
        wT[idx] = v;
    } else if (idx < WTN + 4 * TOWERS * 50 * 16) {
        int k = idx - WTN;
        int l = k / (TOWERS * 50 * 16);
        int r = k % (TOWERS * 50 * 16);
        int t = r / (50 * 16); r %= 50 * 16;
        int j = r / 16, c = r % 16;
        float v = 0.f;
        if (c < 10) v = postW[l * 32500 + (t * FOUT + c) * 650 + j];
        wxT[k] = v;
    }
}

// ------------------------------------------------------------- per layer
// pre-NN: thread o<250 -> ai row o (fp32), 250<=o<500 -> aj row o-250 (fp16).
#define PRE_NT 32
__global__ __launch_bounds__(512) void k_pre(const float* __restrict__ hT,
                                             const float* __restrict__ preW, // [TD][2D]
                                             float* __restrict__ ai,
                                             __half* __restrict__ ajh) {
    __shared__ float xl[PRE_NT * 52];
    int n0 = blockIdx.x * PRE_NT;
    int tid = threadIdx.x;
    for (int k = tid; k < PRE_NT * 52; k += 512) {
        int nl = k & 31, f = k >> 5;
        xl[nl * 52 + f] = (f < 50) ? hT[(size_t)f * NNP + n0 + nl] : 0.f;
    }
    __syncthreads();
    int o = tid;
    if (o < 500) {
        int isj = (o >= 250) ? 1 : 0;
        int oo = o - isj * 250;
        const float* w0 = preW + oo * 100 + isj * 50;
        float w[52];
#pragma unroll
        for (int f = 0; f < 50; ++f) w[f] = w0[f];
        w[50] = 0.f; w[51] = 0.f;
        for (int nl = 0; nl < PRE_NT; ++nl) {
            const float4* xv = (const float4*)&xl[nl * 52];
            float a = 0.f;
#pragma unroll
            for (int j = 0; j < 13; ++j) {
                float4 x4 = xv[j];
                a = fmaf(x4.x, w[4 * j], a);
                a = fmaf(x4.y, w[4 * j + 1], a);
                a = fmaf(x4.z, w[4 * j + 2], a);
                a = fmaf(x4.w, w[4 * j + 3], a);
            }
            if (isj) ajh[(size_t)(n0 + nl) * ASTR + oo] = __float2half(a);
            else     ai[(size_t)(n0 + nl) * ASTR + oo] = a;
        }
    } else {                       // threads 500..511: zero pad cols 250..255
        int p = o - 500;           // 0..11
        if (p < 6) {
            for (int nl = 0; nl < PRE_NT; ++nl)
                ai[(size_t)(n0 + nl) * ASTR + 250 + p] = 0.f;
        } else {
            for (int nl = 0; nl < PRE_NT; ++nl)
                ajh[(size_t)(n0 + nl) * ASTR + 250 + (p - 6)] = __float2half(0.f);
        }
    }
}

#define ACCV(v) do { \
    s1x += v.x; s1y += v.y; s1z += v.z; s1w += v.w; \
    s2x = fmaf(v.x, v.x, s2x); s2y = fmaf(v.y, v.y, s2y); \
    s2z = fmaf(v.z, v.z, s2z); s2w = fmaf(v.w, v.w, s2w); \
    mnx = fminf(mnx, v.x); mny = fminf(mny, v.y); \
    mnz = fminf(mnz, v.z); mnw = fminf(mnw, v.w); \
    mxx = fmaxf(mxx, v.x); mxy = fmaxf(mxy, v.y); \
    mxz = fmaxf(mxz, v.z); mxw = fmaxf(mxw, v.w); \
} while (0)

#define H4TOF4(raw, v) float4 v; do { \
    __half2 h0_ = *(__half2*)&(raw).x; \
    __half2 h1_ = *(__half2*)&(raw).y; \
    float2 f0_ = __half22float2(h0_); \
    float2 f1_ = __half22float2(h1_); \
    v = make_float4(f0_.x, f0_.y, f1_.x, f1_.y); \
} while (0)

// Edge aggregation, RANK space (degree-sorted), fp16 aj gather (8 B/lane),
// 8-way unroll with csr indices software-pipelined one block ahead.
// Grid = 313 nodeblocks x 8 chunks; chunk low bits (XCD); nb reversed.
__global__ __launch_bounds__(512) void k_agg(
    const __half* __restrict__ aj, const int* __restrict__ offs,
    const int* __restrict__ csr_src, const float* __restrict__ ai,
    const float* __restrict__ preB, __half* __restrict__ aggT) {
    int chunk = blockIdx.x & 7;
    int nb = (gridDim.x >> 3) - 1 - (blockIdx.x >> 3);   // reversed
    int tid = threadIdx.x;
    int wave = tid >> 6, lane = tid & 63;
    int g = lane >> 2, q = lane & 3;
    int r = nb * 64 + (wave >> 1) * 16 + g;
    int coloff = chunk * 8 + (wave & 1) * 4 + q;   // 8-B (4-half) column
    bool ok = r < NN;
    int e0 = 0, dg = 0;
    if (ok) { e0 = offs[r]; dg = offs[r + 1] - e0; }
    int mdeg = dg;
#pragma unroll
    for (int o = 4; o < 64; o <<= 1) mdeg = min(mdeg, __shfl_xor(mdeg, o));

    const float2* ajv = (const float2*)aj;   // row = 64 x 8 B
    float s1x = 0.f, s1y = 0.f, s1z = 0.f, s1w = 0.f;
    float s2x = 0.f, s2y = 0.f, s2z = 0.f, s2w = 0.f;
    float mnx = INFINITY, mny = INFINITY, mnz = INFINITY, mnw = INFINITY;
    float mxx = -INFINITY, mxy = -INFINITY, mxz = -INFINITY, mxw = -INFINITY;

    int nblk = mdeg >> 3;
    int spref[8];
    if (nblk > 0) {
#pragma unroll
        for (int k = 0; k < 8; ++k) spref[k] = csr_src[e0 + k];
    }
    for (int b = 0; b < nblk; ++b) {
        int scur[8];
#pragma unroll
        for (int k = 0; k < 8; ++k) scur[k] = spref[k];
        int nxt = (b + 1 < nblk) ? (b + 1) * 8 : 0;   // prefetch next block
#pragma unroll
        for (int k = 0; k < 8; ++k) spref[k] = csr_src[e0 + nxt + k];
        float2 raw[8];
#pragma unroll
        for (int k = 0; k < 8; ++k)
            raw[k] = ajv[((unsigned)scur[k] << 6) + coloff];
#pragma unroll
        for (int k = 0; k < 8; ++k) {
            H4TOF4(raw[k], v);
            ACCV(v);
        }
    }
    int it = nblk << 3;
    for (; it < mdeg; ++it) {
        int s = csr_src[e0 + it];
        float2 rw = ajv[((unsigned)s << 6) + coloff];
        H4TOF4(rw, v);
        ACCV(v);
    }
    while (__any(it < dg)) {                  // tiny tail (bin boundaries)
        bool valid = it < dg;
        int s = csr_src[valid ? e0 + it : e0];
        float2 rw = ajv[((unsigned)s << 6) + coloff];
        H4TOF4(rw, v);
        float zx = valid ? v.x : 0.f, zy = valid ? v.y : 0.f;
        float zz = valid ? v.z : 0.f, zw = valid ? v.w : 0.f;
        s1x += zx; s1y += zy; s1z += zz; s1w += zw;
        s2x = fmaf(zx, zx, s2x); s2y = fmaf(zy, zy, s2y);
        s2z = fmaf(zz, zz, s2z); s2w = fmaf(zw, zw, s2w);
        mnx = fminf(mnx, valid ? v.x : INFINITY);
        mny = fminf(mny, valid ? v.y : INFINITY);
        mnz = fminf(mnz, valid ? v.z : INFINITY);
        mnw = fminf(mnw, valid ? v.w : INFINITY);
        mxx = fmaxf(mxx, valid ? v.x : -INFINITY);
        mxy = fmaxf(mxy, valid ? v.y : -INFINITY);
        mxz = fmaxf(mxz, valid ? v.z : -INFINITY);
        mxw = fmaxf(mxw, valid ? v.w : -INFINITY);
        ++it;
    }

    if (ok) {
        float inv = 1.0f / (float)max(dg, 1);
        float m1a[4], mna[4], mxa[4], sda[4];
        m1a[0] = s1x * inv; m1a[1] = s1y * inv; m1a[2] = s1z * inv; m1a[3] = s1w * inv;
        sda[0] = sqrtf(fmaxf(s2x * inv - m1a[0] * m1a[0], 0.f) + EPS);
        sda[1] = sqrtf(fmaxf(s2y * inv - m1a[1] * m1a[1], 0.f) + EPS);
        sda[2] = sqrtf(fmaxf(s2z * inv - m1a[2] * m1a[2], 0.f) + EPS);
        sda[3] = sqrtf(fmaxf(s2w * inv - m1a[3] * m1a[3], 0.f) + EPS);
        mna[0] = mnx; mna[1] = mny; mna[2] = mnz; mna[3] = mnw;
        mxa[0] = mxx; mxa[1] = mxy; mxa[2] = mxz; mxa[3] = mxw;
        float4 aiv = ((const float4*)ai)[(size_t)r * 64 + coloff];
        float aia[4] = {aiv.x, aiv.y, aiv.z, aiv.w};
        int f0 = coloff * 4;
#pragma unroll
        for (int k = 0; k < 4; ++k) {
            int f = f0 + k;
            if (f < TD) {
                float base;
                if (dg > 0) {
                    base = aia[k] + preB[f];
                } else {
                    base = 0.f;
                    m1a[k] = 0.f; mna[k] = 0.f; mxa[k] = 0.f;
                }
                int t = f / 50, gg = f - t * 50;
                __half* col = aggT + (size_t)(t * 200 + gg) * NNP + r;
                col[0]                 = __float2half(m1a[k] + base);
                col[(size_t)50 * NNP]  = __float2half(mna[k] + base);
                col[(size_t)100 * NNP] = __float2half(mxa[k] + base);
                col[(size_t)150 * NNP] = __float2half(sda[k]);
            }
        }
    }
}

// post-NN: 256 threads = 2 wave-pairs; [0,128) j=0..79 + x-part,
// [128,256) j=80..199 -> partials via padded LDS.
__global__ __launch_bounds__(256) void k_post(
    const float* __restrict__ hT, const __half* __restrict__ aggT,
    const int* __restrict__ offs,
    const float* __restrict__ wT,    // [T][200][32]
    const float* __restrict__ wxT,   // [T][50][16]
    const float* __restrict__ postB, // [50]
    const float* __restrict__ avg_accum, float* __restrict__ yT) {
    __shared__ float dp[128][33];
    int t = blockIdx.x / NGRP2;
    int grp = blockIdx.x - t * NGRP2;
    int tid = threadIdx.x;
    int hf = tid >> 7, ln = tid & 127;
    int hfu = __builtin_amdgcn_readfirstlane(hf);
    int n = grp * 128 + ln;

    float acc[30];
#pragma unroll
    for (int i = 0; i < 30; ++i) acc[i] = 0.f;
    const __half* aggcol = aggT + (size_t)(t * 200) * NNP + n;
    const float4* wv = (const float4*)(wT + t * 200 * 32);
    int j0 = hfu ? 80 : 0;
    int j1 = hfu ? 200 : 80;
#pragma unroll 4
    for (int j = j0; j < j1; ++j) {
        float a = __half2float(aggcol[(size_t)j * NNP]);
        float4 w0 = wv[j * 8 + 0], w1 = wv[j * 8 + 1], w2 = wv[j * 8 + 2],
               w3 = wv[j * 8 + 3], w4 = wv[j * 8 + 4], w5 = wv[j * 8 + 5],
               w6 = wv[j * 8 + 6], w7 = wv[j * 8 + 7];
        acc[0] = fmaf(a, w0.x, acc[0]);   acc[1] = fmaf(a, w0.y, acc[1]);
        acc[2] = fmaf(a, w0.z, acc[2]);   acc[3] = fmaf(a, w0.w, acc[3]);
        acc[4] = fmaf(a, w1.x, acc[4]);   acc[5] = fmaf(a, w1.y, acc[5]);
        acc[6] = fmaf(a, w1.z, acc[6]);   acc[7] = fmaf(a, w1.w, acc[7]);
        acc[8] = fmaf(a, w2.x, acc[8]);   acc[9] = fmaf(a, w2.y, acc[9]);
        acc[10] = fmaf(a, w2.z, acc[10]); acc[11] = fmaf(a, w2.w, acc[11]);
        acc[12] = fmaf(a, w3.x, acc[12]); acc[13] = fmaf(a, w3.y, acc[13]);
        acc[14] = fmaf(a, w3.z, acc[14]); acc[15] = fmaf(a, w3.w, acc[15]);
        acc[16] = fmaf(a, w4.x, acc[16]); acc[17] = fmaf(a, w4.y, acc[17]);
        acc[18] = fmaf(a, w4.z, acc[18]); acc[19] = fmaf(a, w4.w, acc[19]);
        acc[20] = fmaf(a, w5.x, acc[20]); acc[21] = fmaf(a, w5.y, acc[21]);
        acc[22] = fmaf(a, w5.z, acc[22]); acc[23] = fmaf(a, w5.w, acc[23]);
        acc[24] = fmaf(a, w6.x, acc[24]); acc[25] = fmaf(a, w6.y, acc[25]);
        acc[26] = fmaf(a, w6.z, acc[26]); acc[27] = fmaf(a, w6.w, acc[27]);
        acc[28] = fmaf(a, w7.x, acc[28]); acc[29] = fmaf(a, w7.y, acc[29]);
    }
    float xacc[10];
#pragma unroll
    for (int i = 0; i < 10; ++i) xacc[i] = 0.f;
    if (!hfu) {
        const float4* wxv = (const float4*)(wxT + t * 50 * 16);
#pragma unroll 2
        for (int j = 0; j < 50; ++j) {
            float a = hT[(size_t)j * NNP + n];
            float4 x0 = wxv[j * 4 + 0], x1 = wxv[j * 4 + 1], x2 = wxv[j * 4 + 2];
            xacc[0] = fmaf(a, x0.x, xacc[0]); xacc[1] = fmaf(a, x0.y, xacc[1]);
            xacc[2] = fmaf(a, x0.z, xacc[2]); xacc[3] = fmaf(a, x0.w, xacc[3]);
            xacc[4] = fmaf(a, x1.x, xacc[4]); xacc[5] = fmaf(a, x1.y, xacc[5]);
            xacc[6] = fmaf(a, x1.z, xacc[6]); xacc[7] = fmaf(a, x1.w, xacc[7]);
            xacc[8] = fmaf(a, x2.x, xacc[8]); xacc[9] = fmaf(a, x2.y, xacc[9]);
        }
    } else {
#pragma unroll
        for (int g = 0; g < 30; ++g) dp[ln][g] = acc[g];
    }
    __syncthreads();
    if (!hf && n < NN) {
        int dgn = offs[n + 1] - offs[n];
        float cnt = (float)max(dgn, 1);
        float sc = logf(cnt + 1.0f) / (avg_accum[0] * (1.0f / NN));
        float isc = 1.0f / sc;
#pragma unroll
        for (int g = 0; g < 10; ++g) {
            float a0 = acc[g] + dp[ln][g];
            float a1 = acc[10 + g] + dp[ln][10 + g];
            float a2 = acc[20 + g] + dp[ln][20 + g];
            yT[(size_t)(t * FOUT + g) * NNP + n] =
                postB[t * FOUT + g] + xacc[g] + a0 + sc * a1 + isc * a2;
        }
    }
}

// 50x50 linear (pure), LDS-staged weights. 79 blocks x 256 threads.
__global__ __launch_bounds__(256) void k_lin(
    const float* __restrict__ yT, const float* __restrict__ linW,
    const float* __restrict__ linB, float* __restrict__ hrawT) {
    __shared__ float wl[2500];
    __shared__ float bl[50];
    int tid = threadIdx.x;
    int n = blockIdx.x * 256 + tid;
    for (int i = tid; i < 2500; i += 256) wl[i] = linW[i];
    if (tid < 50) bl[tid] = linB[tid];
    __syncthreads();
    float y[50];
#pragma unroll
    for (int q = 0; q < 50; ++q) y[q] = yT[(size_t)q * NNP + n];
    for (int c = 0; c < 50; ++c) {
        float a = bl[c];
        const float* w = wl + c * 50;
#pragma unroll
        for (int q = 0; q < 50; ++q) a = fmaf(w[q], y[q], a);
        hrawT[(size_t)c * NNP + n] = a;
    }
}

// BN stats: one block per channel, coalesced row reduce, direct write.
__global__ __launch_bounds__(256) void k_bnstats(const float* __restrict__ hrawT,
                                                 float* __restrict__ bn) {
    int c = blockIdx.x;
    int tid = threadIdx.x;
    const float* row = hrawT + (size_t)c * NNP;
    float s = 0.f, sq = 0.f;
    for (int n = tid; n < NN; n += 256) {
        float v = row[n];
        s += v; sq = fmaf(v, v, sq);
    }
    for (int o = 32; o > 0; o >>= 1) {
        s += __shfl_down(s, o);
        sq += __shfl_down(sq, o);
    }
    __shared__ float ws[4], wq[4];
    int lane = tid & 63, w = tid >> 6;
    if (lane == 0) { ws[w] = s; wq[w] = sq; }
    __syncthreads();
    if (tid == 0) {
        bn[c] = ws[0] + ws[1] + ws[2] + ws[3];
        bn[50 + c] = wq[0] + wq[1] + wq[2] + wq[3];
    }
}

__global__ void k_bnapply(const float* __restrict__ hrawT, const float* __restrict__ bn,
                          const float* __restrict__ gamma, const float* __restrict__ beta,
                          float* __restrict__ hT) {
    int idx = blockIdx.x * 256 + threadIdx.x;
    if (idx < D * NNP) {
        int c = idx / NNP, n = idx % NNP;
        float mean = bn[c] * (1.0f / NN);
        float var = bn[50 + c] * (1.0f / NN) - mean * mean;
        float v = gamma[c] * (hrawT[idx] - mean) * rsqrtf(var + EPS) + beta[c];
        hT[idx] = (n < NN) ? fmaxf(v, 0.f) : 0.f;
    }
}

__global__ void k_mlp(const float* __restrict__ hT, const int* __restrict__ perm,
                      const float* __restrict__ W1, const float* __restrict__ b1,
                      const float* __restrict__ W2, const float* __restrict__ b2,
                      float* __restrict__ out) {
    int n = blockIdx.x * 256 + threadIdx.x;
    if (n >= NN) return;
    float hv[50];
#pragma unroll
    for (int f = 0; f < 50; ++f) hv[f] = hT[(size_t)f * NNP + n];
    float s = b2[0];
    for (int o = 0; o < 25; ++o) {
        float a = b1[o];
        const float* w = W1 + o * 50;
#pragma unroll
        for (int f = 0; f < 50; ++f) a += w[f] * hv[f];
        s += W2[o] * fmaxf(a, 0.f);
    }
    out[perm[n]] = 1.0f / (1.0f + expf(-s));
}

// ------------------------------------------------------------------ launch
extern "C" void kernel_launch(void* const* d_in, const int* in_sizes, int n_in,
                              void* d_out, int out_size, void* d_ws, size_t ws_size,
                              hipStream_t stream) {
    const int* x = (const int*)d_in[0];
    const int* ei = (const int*)d_in[1];
    const int* src = ei;
    const int* dst = ei + NE;
    const float* emb   = (const float*)d_in[4];
    const float* preW  = (const float*)d_in[5];
    const float* preB  = (const float*)d_in[6];
    const float* postW = (const float*)d_in[7];
    const float* postB = (const float*)d_in[8];
    const float* linW  = (const float*)d_in[9];
    const float* linB  = (const float*)d_in[10];
    const float* gamma = (const float*)d_in[11];
    const float* beta  = (const float*)d_in[12];
    const float* W1 = (const float*)d_in[13];
    const float* b1 = (const float*)d_in[14];
    const float* W2 = (const float*)d_in[15];
    const float* b2 = (const float*)d_in[16];
    float* outp = (float*)d_out;

    char* wsp = (char*)d_ws;
    size_t off = 0;
    auto alloc = [&](size_t bytes) {
        void* p = wsp + off;
        off = (off + bytes + 1023) & ~(size_t)1023;
        return p;
    };
    int* deg     = (int*)alloc(NN * 4);
    int* cursor  = (int*)alloc(NN * 4);
    int* offs    = (int*)alloc((NN + 1) * 4);
    int* csr     = (int*)alloc(NE * 4);
    int* perm    = (int*)alloc(NN * 4);
    int* invp    = (int*)alloc(NN * 4);
    int* deg_r   = (int*)alloc(NN * 4);
    int* hist    = (int*)alloc(256 * 4);
    int* binbase = (int*)alloc(256 * 4);
    int* cursorb = (int*)alloc(256 * 4);
    float* bn    = (float*)alloc(512);     // [0:100) BN stats, [100] avg_log
    float* hT    = (float*)alloc((size_t)D * NNP * 4);
    float* hrawT = (float*)alloc((size_t)D * NNP * 4);
    float* yT    = (float*)alloc((size_t)D * NNP * 4);
    float* ai    = (float*)alloc((size_t)NN * ASTR * 4);
    __half* ajh  = (__half*)alloc((size_t)NN * ASTR * 2);
    float* wT    = (float*)alloc((size_t)4 * TOWERS * 200 * 32 * 4);
    float* wxT   = (float*)alloc((size_t)4 * TOWERS * 50 * 16 * 4);
    __half* aggT = (__half*)alloc((size_t)1000 * NNP * 2);  // fp16 stats+base
    (void)ws_size; (void)in_sizes; (void)n_in; (void)out_size;

    hipMemsetAsync(deg, 0, NN * 4, stream);
    hipMemsetAsync(cursor, 0, NN * 4, stream);
    hipMemsetAsync(hist, 0, 256 * 4, stream);
    hipMemsetAsync(cursorb, 0, 256 * 4, stream);
    hipMemsetAsync(bn, 0, 512, stream);

    k_deg<<<(NE + 255) / 256, 256, 0, stream>>>(dst, deg);
    k_hist<<<(NN + 255) / 256, 256, 0, stream>>>(deg, hist);
    k_binscan<<<1, 256, 0, stream>>>(hist, binbase);
    k_scatter<<<(NN + 255) / 256, 256, 0, stream>>>(deg, binbase, cursorb, perm, invp, deg_r);
    k_scan<<<1, 1024, 0, stream>>>(deg_r, offs);
    k_csr<<<(NE + 255) / 256, 256, 0, stream>>>(src, dst, offs, invp, cursor, csr);
    k_avglog<<<(NN + 255) / 256, 256, 0, stream>>>(deg, bn + 100);
    k_emb<<<(D * NNP + 255) / 256, 256, 0, stream>>>(x, emb, perm, hT);
    k_wt<<<(4 * TOWERS * 200 * 32 + 4 * TOWERS * 50 * 16 + 255) / 256, 256, 0, stream>>>(postW, wT, wxT);

    int aggblocks = 313 * 8;
    for (int l = 0; l < 4; ++l) {
        k_pre<<<NN / PRE_NT, 512, 0, stream>>>(hT, preW + l * TD * 100, ai, ajh);
        k_agg<<<aggblocks, 512, 0, stream>>>(ajh, offs, csr, ai, preB + l * TD, aggT);
        k_post<<<NGRP2 * TOWERS, 256, 0, stream>>>(hT, aggT, offs,
                                                   wT + l * TOWERS * 200 * 32,
                                                   wxT + l * TOWERS * 50 * 16,
                                                   postB + l * 50, bn + 100, yT);
        k_lin<<<NNP / 256, 256, 0, stream>>>(yT, linW + l * 2500, linB + l * 50, hrawT);
        k_bnstats<<<50, 256, 0, stream>>>(hrawT, bn);
        k_bnapply<<<(D * NNP + 255) / 256, 256, 0, stream>>>(hrawT, bn, gamma + l * 50,
                                                             beta + l * 50, hT);
    }
    k_mlp<<<(NN + 255) / 256, 256, 0, stream>>>(hT, perm, W1, b1, W2, b2, outp);
}